// Round 3
// baseline (2138.782 us; speedup 1.0000x reference)
//
#include <hip/hip_runtime.h>

#define N_NODES 50000
#define N_EDGES 1600000
#define NFEAT   512
#define H2      512
#define H3      768
#define NCLASS  64

// ---------------------------------------------------------------------------
// Weight folding:  Wco = W_gc2 @ W_out  [768,64]
//                  Wlo = W_l3  @ W_out  [512,64]
//                  bias_total = b_out + b_l3@W_out + 0.5*b_gc2@W_out  [64]
// blocks 0..191 -> Wco, 192..319 -> Wlo, 320 -> bias
// ---------------------------------------------------------------------------
__global__ __launch_bounds__(256) void fold_weights_kernel(
    const float* __restrict__ Wgc2, const float* __restrict__ Wl3,
    const float* __restrict__ Wout, const float* __restrict__ b_gc2,
    const float* __restrict__ b_l3, const float* __restrict__ b_out,
    float* __restrict__ Wco, float* __restrict__ Wlo, float* __restrict__ bias_total)
{
    const int b = blockIdx.x;
    const int tid = threadIdx.x;
    if (b < 192) {
        int elem = b * 256 + tid;           // 768*64 = 49152
        int r = elem >> 6, c = elem & 63;
        float s = 0.f;
        for (int k = 0; k < H3; ++k)
            s = fmaf(Wgc2[r * H3 + k], Wout[k * NCLASS + c], s);
        Wco[elem] = s;
    } else if (b < 320) {
        int elem = (b - 192) * 256 + tid;   // 512*64 = 32768
        int r = elem >> 6, c = elem & 63;
        float s = 0.f;
        for (int k = 0; k < H3; ++k)
            s = fmaf(Wl3[r * H3 + k], Wout[k * NCLASS + c], s);
        Wlo[elem] = s;
    } else {
        if (tid < NCLASS) {
            float s = b_out[tid];
            for (int k = 0; k < H3; ++k)
                s = fmaf(b_l3[k] + 0.5f * b_gc2[k], Wout[k * NCLASS + tid], s);
            bias_total[tid] = s;
        }
    }
}

// ---------------------------------------------------------------------------
// CSR build: histogram -> exclusive scan -> scatter
// ---------------------------------------------------------------------------
__global__ __launch_bounds__(256) void hist_kernel(const int* __restrict__ rows,
                                                   int* __restrict__ counts)
{
    int e = blockIdx.x * 256 + threadIdx.x;
    if (e < N_EDGES) atomicAdd(&counts[rows[e]], 1);
}

__global__ __launch_bounds__(1024) void scan_kernel(const int* __restrict__ counts,
                                                    int* __restrict__ row_ptr,
                                                    int* __restrict__ row_cur, int n)
{
    __shared__ int wsum[16];
    const int tid  = threadIdx.x;
    const int lane = tid & 63;
    const int wid  = tid >> 6;
    int carry = 0;
    for (int base = 0; base < n; base += 1024) {
        int idx = base + tid;
        int v = (idx < n) ? counts[idx] : 0;
        int x = v;
        #pragma unroll
        for (int off = 1; off < 64; off <<= 1) {
            int y = __shfl_up(x, off, 64);
            if (lane >= off) x += y;
        }
        if (lane == 63) wsum[wid] = x;
        __syncthreads();
        if (wid == 0) {
            int w = (lane < 16) ? wsum[lane] : 0;
            #pragma unroll
            for (int off = 1; off < 16; off <<= 1) {
                int y = __shfl_up(w, off, 64);
                if (lane >= off) w += y;
            }
            if (lane < 16) wsum[lane] = w;   // inclusive per-wave totals
        }
        __syncthreads();
        int wave_off = (wid > 0) ? wsum[wid - 1] : 0;
        int excl = x - v + wave_off;
        if (idx < n) {
            int o = carry + excl;
            row_ptr[idx] = o;
            row_cur[idx] = o;
        }
        int total = wsum[15];
        __syncthreads();                     // protect wsum for next chunk
        carry += total;
    }
    if (tid == 0) row_ptr[n] = carry;
}

__global__ __launch_bounds__(256) void scatter_kernel(
    const int* __restrict__ rows, const int* __restrict__ cols,
    const float* __restrict__ vals, int* __restrict__ row_cur,
    int* __restrict__ cols_s, float* __restrict__ vals_s)
{
    int e = blockIdx.x * 256 + threadIdx.x;
    if (e < N_EDGES) {
        int r = rows[e];
        int p = atomicAdd(&row_cur[r], 1);
        cols_s[p] = cols[e];
        vals_s[p] = vals[e];
    }
}

// ---------------------------------------------------------------------------
// Tiled fp32 GEMM:  C[M,N] = A[M,K] @ B[K,N] (+ epilogue)
// EPI: 0 none | 1 +bias | 2 +bias,relu | 3 +bias + 0.5*extra
// Requires N%BN==0, K%BK==0; M guarded. 256 threads.
// A staged transposed As[BK][BM+4]; fragment split in halves for b128 reads.
// ---------------------------------------------------------------------------
template <int BM, int BN, int BK, int TM, int TN, int EPI>
__global__ __launch_bounds__(256, 4) void gemm_tiled(
    const float* __restrict__ A, const float* __restrict__ B,
    const float* __restrict__ bias, const float* __restrict__ extra,
    float* __restrict__ C, int M, int N, int K)
{
    static_assert((BM / TM) * (BN / TN) == 256, "256 threads");
    __shared__ float As[BK][BM + 4];
    __shared__ float Bs[BK][BN + 4];

    const int tid = threadIdx.x;
    const int tr = tid / (BN / TN);
    const int tc = tid % (BN / TN);
    const int m0 = blockIdx.x * BM;
    const int n0 = blockIdx.y * BN;

    float acc[TM][TN];
    #pragma unroll
    for (int i = 0; i < TM; ++i)
        #pragma unroll
        for (int j = 0; j < TN; ++j) acc[i][j] = 0.f;

    for (int k0 = 0; k0 < K; k0 += BK) {
        // ---- stage A (transposed) ----
        #pragma unroll
        for (int p = 0; p < BM * BK / 4 / 256; ++p) {
            int t = tid + p * 256;
            int r  = t / (BK / 4);
            int c4 = (t % (BK / 4)) * 4;
            float4 v = make_float4(0.f, 0.f, 0.f, 0.f);
            if (m0 + r < M)
                v = *(const float4*)&A[(size_t)(m0 + r) * K + k0 + c4];
            As[c4 + 0][r] = v.x; As[c4 + 1][r] = v.y;
            As[c4 + 2][r] = v.z; As[c4 + 3][r] = v.w;
        }
        // ---- stage B ----
        #pragma unroll
        for (int p = 0; p < BK * BN / 4 / 256; ++p) {
            int t = tid + p * 256;
            int kk = t / (BN / 4);
            int c4 = (t % (BN / 4)) * 4;
            *(float4*)&Bs[kk][c4] =
                *(const float4*)&B[(size_t)(k0 + kk) * N + n0 + c4];
        }
        __syncthreads();

        #pragma unroll
        for (int kk = 0; kk < BK; ++kk) {
            float a[TM], b[TN];
            *(float4*)&a[0] = *(const float4*)&As[kk][tr * 4];
            if constexpr (TM == 8)
                *(float4*)&a[4] = *(const float4*)&As[kk][BM / 2 + tr * 4];
            *(float4*)&b[0] = *(const float4*)&Bs[kk][tc * 4];
            if constexpr (TN == 8)
                *(float4*)&b[4] = *(const float4*)&Bs[kk][BN / 2 + tc * 4];
            #pragma unroll
            for (int i = 0; i < TM; ++i)
                #pragma unroll
                for (int j = 0; j < TN; ++j)
                    acc[i][j] = fmaf(a[i], b[j], acc[i][j]);
        }
        __syncthreads();
    }

    // ---- epilogue ----
    #pragma unroll
    for (int i = 0; i < TM; ++i) {
        int m = m0 + (i >> 2) * (BM / 2) + tr * 4 + (i & 3);
        if (m >= M) continue;
        #pragma unroll
        for (int jq = 0; jq < TN / 4; ++jq) {
            int n = n0 + jq * (BN / 2) + tc * 4;
            float4 o = make_float4(acc[i][jq * 4 + 0], acc[i][jq * 4 + 1],
                                   acc[i][jq * 4 + 2], acc[i][jq * 4 + 3]);
            if constexpr (EPI == 1 || EPI == 2) {
                o.x += bias[n + 0]; o.y += bias[n + 1];
                o.z += bias[n + 2]; o.w += bias[n + 3];
            }
            if constexpr (EPI == 2) {
                o.x = fmaxf(o.x, 0.f); o.y = fmaxf(o.y, 0.f);
                o.z = fmaxf(o.z, 0.f); o.w = fmaxf(o.w, 0.f);
            }
            if constexpr (EPI == 3) {
                float4 e = *(const float4*)&extra[(size_t)m * N + n];
                o.x += bias[n + 0] + 0.5f * e.x;
                o.y += bias[n + 1] + 0.5f * e.y;
                o.z += bias[n + 2] + 0.5f * e.z;
                o.w += bias[n + 3] + 0.5f * e.w;
            }
            *(float4*)&C[(size_t)m * N + n] = o;
        }
    }
}

// ---------------------------------------------------------------------------
// CSR SpMM, 512 cols: 2 rows per 256-thread block (128 thr * float4 per row),
// 4-edge-deep unroll for memory-level parallelism on the random row gather.
// ---------------------------------------------------------------------------
__global__ __launch_bounds__(256) void spmm_csr512(
    const int* __restrict__ row_ptr, const int* __restrict__ cols,
    const float* __restrict__ vals, const float* __restrict__ dense,
    float* __restrict__ out)
{
    const int row = blockIdx.x * 2 + (threadIdx.x >> 7);
    const int t4 = (threadIdx.x & 127) * 4;
    int e = row_ptr[row];
    const int e1 = row_ptr[row + 1];
    float4 acc = make_float4(0.f, 0.f, 0.f, 0.f);
    for (; e + 4 <= e1; e += 4) {
        int c0 = cols[e],     c1 = cols[e + 1];
        int c2 = cols[e + 2], c3 = cols[e + 3];
        float v0 = vals[e],     v1 = vals[e + 1];
        float v2 = vals[e + 2], v3 = vals[e + 3];
        float4 d0 = *(const float4*)&dense[(size_t)c0 * 512 + t4];
        float4 d1 = *(const float4*)&dense[(size_t)c1 * 512 + t4];
        float4 d2 = *(const float4*)&dense[(size_t)c2 * 512 + t4];
        float4 d3 = *(const float4*)&dense[(size_t)c3 * 512 + t4];
        acc.x = fmaf(v0, d0.x, fmaf(v1, d1.x, fmaf(v2, d2.x, fmaf(v3, d3.x, acc.x))));
        acc.y = fmaf(v0, d0.y, fmaf(v1, d1.y, fmaf(v2, d2.y, fmaf(v3, d3.y, acc.y))));
        acc.z = fmaf(v0, d0.z, fmaf(v1, d1.z, fmaf(v2, d2.z, fmaf(v3, d3.z, acc.z))));
        acc.w = fmaf(v0, d0.w, fmaf(v1, d1.w, fmaf(v2, d2.w, fmaf(v3, d3.w, acc.w))));
    }
    for (; e < e1; ++e) {
        int c = cols[e]; float v = vals[e];
        float4 d = *(const float4*)&dense[(size_t)c * 512 + t4];
        acc.x = fmaf(v, d.x, acc.x); acc.y = fmaf(v, d.y, acc.y);
        acc.z = fmaf(v, d.z, acc.z); acc.w = fmaf(v, d.w, acc.w);
    }
    *(float4*)&out[(size_t)row * 512 + t4] = acc;
}

// CSR SpMM, 64 cols: 4 rows per 256-thread block (64 lanes per row).
__global__ __launch_bounds__(256) void spmm_csr64(
    const int* __restrict__ row_ptr, const int* __restrict__ cols,
    const float* __restrict__ vals, const float* __restrict__ dense,
    float* __restrict__ out)
{
    const int row = blockIdx.x * 4 + (threadIdx.x >> 6);
    const int c = threadIdx.x & 63;
    int e = row_ptr[row];
    const int e1 = row_ptr[row + 1];
    float acc0 = 0.f, acc1 = 0.f;
    for (; e + 2 <= e1; e += 2) {
        acc0 = fmaf(vals[e],     dense[(size_t)cols[e]     * 64 + c], acc0);
        acc1 = fmaf(vals[e + 1], dense[(size_t)cols[e + 1] * 64 + c], acc1);
    }
    if (e < e1) acc0 = fmaf(vals[e], dense[(size_t)cols[e] * 64 + c], acc0);
    out[(size_t)row * 64 + c] = acc0 + acc1;
}

// ---------------------------------------------------------------------------
// Global min/max + normalize
// ---------------------------------------------------------------------------
__global__ __launch_bounds__(256) void minmax_partial(const float* __restrict__ x,
                                                      int n, float* __restrict__ part)
{
    float mn = 3.4e38f, mx = -3.4e38f;
    for (int i = blockIdx.x * 256 + threadIdx.x; i < n; i += gridDim.x * 256) {
        float v = x[i];
        mn = fminf(mn, v); mx = fmaxf(mx, v);
    }
    #pragma unroll
    for (int off = 32; off > 0; off >>= 1) {
        mn = fminf(mn, __shfl_down(mn, off, 64));
        mx = fmaxf(mx, __shfl_down(mx, off, 64));
    }
    __shared__ float smn[4], smx[4];
    if ((threadIdx.x & 63) == 0) { smn[threadIdx.x >> 6] = mn; smx[threadIdx.x >> 6] = mx; }
    __syncthreads();
    if (threadIdx.x == 0) {
        mn = fminf(fminf(smn[0], smn[1]), fminf(smn[2], smn[3]));
        mx = fmaxf(fmaxf(smx[0], smx[1]), fmaxf(smx[2], smx[3]));
        part[blockIdx.x] = mn;
        part[gridDim.x + blockIdx.x] = mx;
    }
}

__global__ __launch_bounds__(256) void minmax_final(const float* __restrict__ part,
                                                    float* __restrict__ mm)
{
    float mn = part[threadIdx.x], mx = part[256 + threadIdx.x];
    #pragma unroll
    for (int off = 32; off > 0; off >>= 1) {
        mn = fminf(mn, __shfl_down(mn, off, 64));
        mx = fmaxf(mx, __shfl_down(mx, off, 64));
    }
    __shared__ float smn[4], smx[4];
    if ((threadIdx.x & 63) == 0) { smn[threadIdx.x >> 6] = mn; smx[threadIdx.x >> 6] = mx; }
    __syncthreads();
    if (threadIdx.x == 0) {
        mm[0] = fminf(fminf(smn[0], smn[1]), fminf(smn[2], smn[3]));
        mm[1] = fmaxf(fmaxf(smx[0], smx[1]), fmaxf(smx[2], smx[3]));
    }
}

__global__ __launch_bounds__(256) void normalize_kernel(float4* __restrict__ x, int n4,
                                                        const float* __restrict__ mm)
{
    int i = blockIdx.x * 256 + threadIdx.x;
    if (i >= n4) return;
    float mn = mm[0];
    float s = 2.0f / (mm[1] - mn);
    float4 v = x[i];
    v.x = fmaf(v.x - mn, s, -1.f);
    v.y = fmaf(v.y - mn, s, -1.f);
    v.z = fmaf(v.z - mn, s, -1.f);
    v.w = fmaf(v.w - mn, s, -1.f);
    x[i] = v;
}

// ---------------------------------------------------------------------------
extern "C" void kernel_launch(void* const* d_in, const int* in_sizes, int n_in,
                              void* d_out, int out_size, void* d_ws, size_t ws_size,
                              hipStream_t stream)
{
    const float* x       = (const float*)d_in[0];
    const int*   adj_row = (const int*)d_in[1];
    const int*   adj_col = (const int*)d_in[2];
    const float* adj_val = (const float*)d_in[3];
    const float* W_org = (const float*)d_in[4];
    const float* b_org = (const float*)d_in[5];
    const float* W_gc1 = (const float*)d_in[6];
    const float* b_gc1 = (const float*)d_in[7];
    const float* W_gc2 = (const float*)d_in[8];
    const float* b_gc2 = (const float*)d_in[9];
    const float* W_l3  = (const float*)d_in[10];
    const float* b_l3  = (const float*)d_in[11];
    const float* W_out = (const float*)d_in[12];
    const float* b_out = (const float*)d_in[13];
    float* out = (float*)d_out;

    // ---- workspace carve-up (256B aligned) ----
    char* w = (char*)d_ws;
    size_t off = 0;
    auto alloc = [&](size_t bytes) -> void* {
        void* p = w + off;
        off += (bytes + 255) & ~(size_t)255;
        return p;
    };
    float* h     = (float*)alloc((size_t)N_NODES * H2 * 4);     // 102.4 MB
    float* ah    = (float*)alloc((size_t)N_NODES * H2 * 4);     // 102.4 MB
    float* g     = (float*)alloc((size_t)N_NODES * H3 * 4);     // 153.6 MB
    float* s     = (float*)alloc((size_t)N_NODES * NCLASS * 4); // 12.8 MB
    float* as_   = (float*)alloc((size_t)N_NODES * NCLASS * 4); // 12.8 MB
    int*   counts  = (int*)alloc((size_t)N_NODES * 4);
    int*   row_ptr = (int*)alloc((size_t)(N_NODES + 1) * 4);
    int*   row_cur = (int*)alloc((size_t)N_NODES * 4);
    int*   cols_s  = (int*)alloc((size_t)N_EDGES * 4);
    float* vals_s  = (float*)alloc((size_t)N_EDGES * 4);
    float* Wco = (float*)alloc((size_t)H3 * NCLASS * 4);
    float* Wlo = (float*)alloc((size_t)H2 * NCLASS * 4);
    float* bias_total = (float*)alloc(NCLASS * 4);
    float* part = (float*)alloc(512 * 4);
    float* mm   = (float*)alloc(2 * 4);
    (void)ws_size; (void)n_in; (void)in_sizes; (void)out_size;

    // ---- CSR build + weight folds ----
    hipMemsetAsync(counts, 0, (size_t)N_NODES * 4, stream);
    fold_weights_kernel<<<321, 256, 0, stream>>>(W_gc2, W_l3, W_out, b_gc2, b_l3,
                                                 b_out, Wco, Wlo, bias_total);
    hist_kernel<<<N_EDGES / 256, 256, 0, stream>>>(adj_row, counts);
    scan_kernel<<<1, 1024, 0, stream>>>(counts, row_ptr, row_cur, N_NODES);
    scatter_kernel<<<N_EDGES / 256, 256, 0, stream>>>(adj_row, adj_col, adj_val,
                                                      row_cur, cols_s, vals_s);

    const int MB128 = (N_NODES + 127) / 128;  // 391
    const int MB64  = (N_NODES + 63) / 64;    // 782

    // h = x @ W_org + b_org            [N,512]
    gemm_tiled<128, 128, 32, 8, 8, 1><<<dim3(MB128, 4), 256, 0, stream>>>(
        x, W_org, b_org, nullptr, h, N_NODES, H2, NFEAT);
    // ah = adj @ h                     [N,512]
    spmm_csr512<<<N_NODES / 2, 256, 0, stream>>>(row_ptr, cols_s, vals_s, h, ah);
    // g = relu(ah @ W_gc1 + b_gc1)     [N,768]
    gemm_tiled<128, 128, 32, 8, 8, 2><<<dim3(MB128, 6), 256, 0, stream>>>(
        ah, W_gc1, b_gc1, nullptr, g, N_NODES, H3, H2);
    // s = g @ Wco                      [N,64]
    gemm_tiled<64, 64, 32, 4, 4, 0><<<dim3(MB64, 1), 256, 0, stream>>>(
        g, Wco, nullptr, nullptr, s, N_NODES, NCLASS, H3);
    // as = adj @ s                     [N,64]
    spmm_csr64<<<N_NODES / 4, 256, 0, stream>>>(row_ptr, cols_s, vals_s, s, as_);
    // out = h @ Wlo + 0.5*as + bias_total  [N,64]
    gemm_tiled<64, 64, 32, 4, 4, 3><<<dim3(MB64, 1), 256, 0, stream>>>(
        h, Wlo, bias_total, as_, out, N_NODES, NCLASS, H2);

    // ---- global min-max normalize ----
    const int n_out = N_NODES * NCLASS;
    minmax_partial<<<256, 256, 0, stream>>>(out, n_out, part);
    minmax_final<<<1, 256, 0, stream>>>(part, mm);
    normalize_kernel<<<(n_out / 4 + 255) / 256, 256, 0, stream>>>(
        (float4*)out, n_out / 4, mm);
}

// Round 5
// 1430.443 us; speedup vs baseline: 1.4952x; 1.4952x over previous
//
#include <hip/hip_runtime.h>

#define N_NODES 50000
#define N_EDGES 1600000
#define NFEAT   512
#define H2      512
#define H3      768
#define NCLASS  64

typedef __attribute__((ext_vector_type(8))) short bf16x8;
typedef __attribute__((ext_vector_type(4))) float f32x4;

// ---------------------------------------------------------------------------
// bf16 split helpers (round-to-nearest-even)
// ---------------------------------------------------------------------------
__device__ __forceinline__ unsigned short f2bf(float f) {
    unsigned u = __builtin_bit_cast(unsigned, f);
    unsigned r = (u + 0x7FFF + ((u >> 16) & 1)) >> 16;
    return (unsigned short)r;
}
__device__ __forceinline__ float bf2f(unsigned short h) {
    unsigned u = ((unsigned)h) << 16;
    return __builtin_bit_cast(float, u);
}

__device__ __forceinline__ void gload_lds16(const void* g, void* l) {
    __builtin_amdgcn_global_load_lds(
        (const __attribute__((address_space(1))) void*)g,
        (__attribute__((address_space(3))) void*)l, 16, 0, 0);
}

// ---------------------------------------------------------------------------
// Weight folding:  Wco = W_gc2 @ W_out  [768,64]
//                  Wlo = W_l3  @ W_out  [512,64]
//                  bias_total = b_out + b_l3@W_out + 0.5*b_gc2@W_out  [64]
// ---------------------------------------------------------------------------
__global__ __launch_bounds__(256) void fold_weights_kernel(
    const float* __restrict__ Wgc2, const float* __restrict__ Wl3,
    const float* __restrict__ Wout, const float* __restrict__ b_gc2,
    const float* __restrict__ b_l3, const float* __restrict__ b_out,
    float* __restrict__ Wco, float* __restrict__ Wlo, float* __restrict__ bias_total)
{
    const int b = blockIdx.x;
    const int tid = threadIdx.x;
    if (b < 192) {
        int elem = b * 256 + tid;           // 768*64
        int r = elem >> 6, c = elem & 63;
        float s = 0.f;
        for (int k = 0; k < H3; ++k)
            s = fmaf(Wgc2[r * H3 + k], Wout[k * NCLASS + c], s);
        Wco[elem] = s;
    } else if (b < 320) {
        int elem = (b - 192) * 256 + tid;   // 512*64
        int r = elem >> 6, c = elem & 63;
        float s = 0.f;
        for (int k = 0; k < H3; ++k)
            s = fmaf(Wl3[r * H3 + k], Wout[k * NCLASS + c], s);
        Wlo[elem] = s;
    } else {
        if (tid < NCLASS) {
            float s = b_out[tid];
            for (int k = 0; k < H3; ++k)
                s = fmaf(b_l3[k] + 0.5f * b_gc2[k], Wout[k * NCLASS + tid], s);
            bias_total[tid] = s;
        }
    }
}

// ---------------------------------------------------------------------------
// Weight prep: transpose to [N][K] and split into bf16 hi/lo.
//   seg0: WorgT [512][512] <- W_org [512][512]
//   seg1: Wgc1T [768][512] <- W_gc1 [512][768]
//   seg2: WcoT  [64][768]  <- Wco   [768][64]
//   seg3: WloT  [64][512]  <- Wlo   [512][64]
// ---------------------------------------------------------------------------
__global__ __launch_bounds__(256) void prep_weights_kernel(
    const float* __restrict__ Worg, const float* __restrict__ Wgc1,
    const float* __restrict__ Wco, const float* __restrict__ Wlo,
    unsigned short* __restrict__ WorgT_hi, unsigned short* __restrict__ WorgT_lo,
    unsigned short* __restrict__ Wgc1T_hi, unsigned short* __restrict__ Wgc1T_lo,
    unsigned short* __restrict__ WcoT_hi,  unsigned short* __restrict__ WcoT_lo,
    unsigned short* __restrict__ WloT_hi,  unsigned short* __restrict__ WloT_lo)
{
    int e = blockIdx.x * 256 + threadIdx.x;
    float v; unsigned short* hi; unsigned short* lo; int idx;
    if (e < 262144) {                       // WorgT
        int n = e >> 9, k = e & 511;
        v = Worg[k * H2 + n]; hi = WorgT_hi; lo = WorgT_lo; idx = e;
    } else if (e < 262144 + 393216) {       // Wgc1T
        int e2 = e - 262144;
        int n = e2 >> 9, k = e2 & 511;
        v = Wgc1[k * H3 + n]; hi = Wgc1T_hi; lo = Wgc1T_lo; idx = e2;
    } else if (e < 262144 + 393216 + 49152) { // WcoT
        int e3 = e - 262144 - 393216;
        int n = e3 / H3, k = e3 % H3;
        v = Wco[k * NCLASS + n]; hi = WcoT_hi; lo = WcoT_lo; idx = e3;
    } else if (e < 262144 + 393216 + 49152 + 32768) { // WloT
        int e4 = e - 262144 - 393216 - 49152;
        int n = e4 >> 9, k = e4 & 511;
        v = Wlo[k * NCLASS + n]; hi = WloT_hi; lo = WloT_lo; idx = e4;
    } else return;
    unsigned short hv = f2bf(v);
    hi[idx] = hv;
    lo[idx] = f2bf(v - bf2f(hv));
}

// ---------------------------------------------------------------------------
// CSR build: histogram -> exclusive scan -> scatter
// ---------------------------------------------------------------------------
__global__ __launch_bounds__(256) void hist_kernel(const int* __restrict__ rows,
                                                   int* __restrict__ counts)
{
    int e = blockIdx.x * 256 + threadIdx.x;
    if (e < N_EDGES) atomicAdd(&counts[rows[e]], 1);
}

__global__ __launch_bounds__(1024) void scan_kernel(const int* __restrict__ counts,
                                                    int* __restrict__ row_ptr,
                                                    int* __restrict__ row_cur, int n)
{
    __shared__ int wsum[16];
    const int tid  = threadIdx.x;
    const int lane = tid & 63;
    const int wid  = tid >> 6;
    int carry = 0;
    for (int base = 0; base < n; base += 1024) {
        int idx = base + tid;
        int v = (idx < n) ? counts[idx] : 0;
        int x = v;
        #pragma unroll
        for (int off = 1; off < 64; off <<= 1) {
            int y = __shfl_up(x, off, 64);
            if (lane >= off) x += y;
        }
        if (lane == 63) wsum[wid] = x;
        __syncthreads();
        if (wid == 0) {
            int w = (lane < 16) ? wsum[lane] : 0;
            #pragma unroll
            for (int off = 1; off < 16; off <<= 1) {
                int y = __shfl_up(w, off, 64);
                if (lane >= off) w += y;
            }
            if (lane < 16) wsum[lane] = w;
        }
        __syncthreads();
        int wave_off = (wid > 0) ? wsum[wid - 1] : 0;
        int excl = x - v + wave_off;
        if (idx < n) {
            int o = carry + excl;
            row_ptr[idx] = o;
            row_cur[idx] = o;
        }
        int total = wsum[15];
        __syncthreads();
        carry += total;
    }
    if (tid == 0) row_ptr[n] = carry;
}

__global__ __launch_bounds__(256) void scatter_kernel(
    const int* __restrict__ rows, const int* __restrict__ cols,
    const float* __restrict__ vals, int* __restrict__ row_cur,
    int* __restrict__ cols_s, float* __restrict__ vals_s)
{
    int e = blockIdx.x * 256 + threadIdx.x;
    if (e < N_EDGES) {
        int r = rows[e];
        int p = atomicAdd(&row_cur[r], 1);
        cols_s[p] = cols[e];
        vals_s[p] = vals[e];
    }
}

// ---------------------------------------------------------------------------
// MFMA bf16-split-3 GEMM.  C[M,N] = A[M,K] @ B[K,N] (+ epilogue)
// BM=128 fixed, 4 waves (2x2), wave tile 64 x BN/2, frags 16x16x32.
// B given transposed+split: Bhi/Blo [N][K] bf16.
// A either fp32 [M][K] (A_F32: in-register split staging) or pair Ahi/Alo.
// LDS 1KB chunks, fragment-major: chunk layout [Ahi 8][Alo 8][Bhi BF][Blo BF].
// EPI: 0 none | 1 +bias | 2 +bias,relu | 3 +bias+0.5*extra
// ---------------------------------------------------------------------------
template <int BN, int EPI, bool A_F32, bool WPAIR, bool WF32>
__global__ __launch_bounds__(256, 2) void gemm_mfma(
    const float* __restrict__ Af,
    const unsigned short* __restrict__ Ahi, const unsigned short* __restrict__ Alo,
    const unsigned short* __restrict__ Bhi, const unsigned short* __restrict__ Blo,
    const float* __restrict__ bias, const float* __restrict__ extra,
    float* __restrict__ Cf, unsigned short* __restrict__ Chi,
    unsigned short* __restrict__ Clo,
    int M, int N, int K, int NB)
{
    constexpr int WNF = BN / 32;          // n-frags per wave
    constexpr int BF  = BN / 16;          // B n-frags per tile
    constexpr int NCH = 16 + 2 * BF;      // 1KB LDS chunks
    __shared__ unsigned short lds[NCH * 512];

    const int tid  = threadIdx.x;
    const int lane = tid & 63;
    const int wid  = tid >> 6;
    const int wr   = wid >> 1, wc = wid & 1;
    const int fr   = lane & 15;           // frag row (A) / col (B)
    const int fk   = (lane >> 4) * 8;     // frag k-offset

    // bijective XCD-chunked block swizzle (m204)
    const int nwg = gridDim.x;
    const int u = blockIdx.x;
    const int q = nwg >> 3, r = nwg & 7;
    const int xcd = u & 7, pos = u >> 3;
    const int wg = (xcd < r ? xcd * (q + 1) : r * (q + 1) + (xcd - r) * q) + pos;
    const int m0 = (wg / NB) * 128;
    const int n0 = (wg % NB) * BN;

    f32x4 acc[4][WNF];
    #pragma unroll
    for (int mi = 0; mi < 4; ++mi)
        #pragma unroll
        for (int ni = 0; ni < WNF; ++ni)
            acc[mi][ni] = (f32x4){0.f, 0.f, 0.f, 0.f};

    for (int kt = 0; kt < K; kt += 32) {
        if constexpr (A_F32) {
            // A: load fp32, split in-register, ds_write fragment-major
            #pragma unroll
            for (int sub = wid; sub < 8; sub += 4) {
                int row = m0 + sub * 16 + fr;
                if (row >= M) row = M - 1;
                const float* src = Af + (size_t)row * K + kt + fk;
                float4 p0 = *(const float4*)src;
                float4 p1 = *(const float4*)(src + 4);
                float v[8] = {p0.x, p0.y, p0.z, p0.w, p1.x, p1.y, p1.z, p1.w};
                bf16x8 h8, l8;
                #pragma unroll
                for (int j = 0; j < 8; ++j) {
                    unsigned short hv = f2bf(v[j]);
                    h8[j] = (short)hv;
                    l8[j] = (short)f2bf(v[j] - bf2f(hv));
                }
                *(bf16x8*)&lds[sub * 512 + lane * 8] = h8;
                *(bf16x8*)&lds[(8 + sub) * 512 + lane * 8] = l8;
            }
            for (int ch = 16 + wid; ch < NCH; ch += 4) {
                int bch = ch - 16;
                int sub = bch % BF;
                const unsigned short* base = (bch < BF) ? Bhi : Blo;
                int col = n0 + sub * 16 + fr;
                gload_lds16(base + (size_t)col * K + kt + fk, &lds[ch * 512]);
            }
        } else {
            for (int ch = wid; ch < NCH; ch += 4) {
                const unsigned short* src;
                if (ch < 16) {
                    int sub = ch & 7;
                    int row = m0 + sub * 16 + fr;
                    if (row >= M) row = M - 1;
                    const unsigned short* base = (ch < 8) ? Ahi : Alo;
                    src = base + (size_t)row * K + kt + fk;
                } else {
                    int bch = ch - 16;
                    int sub = bch % BF;
                    const unsigned short* base = (bch < BF) ? Bhi : Blo;
                    int col = n0 + sub * 16 + fr;
                    src = base + (size_t)col * K + kt + fk;
                }
                gload_lds16(src, &lds[ch * 512]);
            }
        }
        __syncthreads();

        bf16x8 ah[4], al[4], bh[WNF], bl[WNF];
        #pragma unroll
        for (int mi = 0; mi < 4; ++mi) {
            int mf = wr * 4 + mi;
            ah[mi] = *(const bf16x8*)&lds[mf * 512 + lane * 8];
            al[mi] = *(const bf16x8*)&lds[(8 + mf) * 512 + lane * 8];
        }
        #pragma unroll
        for (int ni = 0; ni < WNF; ++ni) {
            int nf = wc * WNF + ni;
            bh[ni] = *(const bf16x8*)&lds[(16 + nf) * 512 + lane * 8];
            bl[ni] = *(const bf16x8*)&lds[(16 + BF + nf) * 512 + lane * 8];
        }
        #pragma unroll
        for (int mi = 0; mi < 4; ++mi)
            #pragma unroll
            for (int ni = 0; ni < WNF; ++ni) {
                acc[mi][ni] = __builtin_amdgcn_mfma_f32_16x16x32_bf16(
                    ah[mi], bh[ni], acc[mi][ni], 0, 0, 0);
                acc[mi][ni] = __builtin_amdgcn_mfma_f32_16x16x32_bf16(
                    ah[mi], bl[ni], acc[mi][ni], 0, 0, 0);
                acc[mi][ni] = __builtin_amdgcn_mfma_f32_16x16x32_bf16(
                    al[mi], bh[ni], acc[mi][ni], 0, 0, 0);
            }
        __syncthreads();
    }

    // epilogue: C/D mapping col=lane&15, row=(lane>>4)*4+reg  [m89/m91]
    const int r0 = m0 + wr * 64 + (lane >> 4) * 4;
    const int c0 = n0 + wc * (BN / 2) + (lane & 15);
    #pragma unroll
    for (int mi = 0; mi < 4; ++mi)
        #pragma unroll
        for (int ni = 0; ni < WNF; ++ni) {
            int col = c0 + ni * 16;
            float bv = 0.f;
            if constexpr (EPI > 0) bv = bias[col];
            #pragma unroll
            for (int qi = 0; qi < 4; ++qi) {
                int row = r0 + mi * 16 + qi;
                if (row >= M) continue;
                float v = acc[mi][ni][qi] + bv;
                if constexpr (EPI == 2) v = fmaxf(v, 0.f);
                if constexpr (EPI == 3)
                    v = fmaf(0.5f, extra[(size_t)row * N + col], v);
                size_t idx = (size_t)row * N + col;
                if constexpr (WF32) Cf[idx] = v;
                if constexpr (WPAIR) {
                    unsigned short hv = f2bf(v);
                    Chi[idx] = hv;
                    Clo[idx] = f2bf(v - bf2f(hv));
                }
            }
        }
}

// ---------------------------------------------------------------------------
// CSR SpMM, 512 cols: 2 rows / 256-thread block, gathers fp32, writes bf16 pair
// ---------------------------------------------------------------------------
__global__ __launch_bounds__(256) void spmm_csr512_pair(
    const int* __restrict__ row_ptr, const int* __restrict__ cols,
    const float* __restrict__ vals, const float* __restrict__ dense,
    unsigned short* __restrict__ out_hi, unsigned short* __restrict__ out_lo)
{
    const int row = blockIdx.x * 2 + (threadIdx.x >> 7);
    const int t4 = (threadIdx.x & 127) * 4;
    int e = row_ptr[row];
    const int e1 = row_ptr[row + 1];
    float4 acc = make_float4(0.f, 0.f, 0.f, 0.f);
    for (; e + 4 <= e1; e += 4) {
        int c0 = cols[e],     c1 = cols[e + 1];
        int c2 = cols[e + 2], c3 = cols[e + 3];
        float v0 = vals[e],     v1 = vals[e + 1];
        float v2 = vals[e + 2], v3 = vals[e + 3];
        float4 d0 = *(const float4*)&dense[(size_t)c0 * 512 + t4];
        float4 d1 = *(const float4*)&dense[(size_t)c1 * 512 + t4];
        float4 d2 = *(const float4*)&dense[(size_t)c2 * 512 + t4];
        float4 d3 = *(const float4*)&dense[(size_t)c3 * 512 + t4];
        acc.x = fmaf(v0, d0.x, fmaf(v1, d1.x, fmaf(v2, d2.x, fmaf(v3, d3.x, acc.x))));
        acc.y = fmaf(v0, d0.y, fmaf(v1, d1.y, fmaf(v2, d2.y, fmaf(v3, d3.y, acc.y))));
        acc.z = fmaf(v0, d0.z, fmaf(v1, d1.z, fmaf(v2, d2.z, fmaf(v3, d3.z, acc.z))));
        acc.w = fmaf(v0, d0.w, fmaf(v1, d1.w, fmaf(v2, d2.w, fmaf(v3, d3.w, acc.w))));
    }
    for (; e < e1; ++e) {
        int c = cols[e]; float v = vals[e];
        float4 d = *(const float4*)&dense[(size_t)c * 512 + t4];
        acc.x = fmaf(v, d.x, acc.x); acc.y = fmaf(v, d.y, acc.y);
        acc.z = fmaf(v, d.z, acc.z); acc.w = fmaf(v, d.w, acc.w);
    }
    ushort4 h4, l4;
    h4.x = f2bf(acc.x); l4.x = f2bf(acc.x - bf2f(h4.x));
    h4.y = f2bf(acc.y); l4.y = f2bf(acc.y - bf2f(h4.y));
    h4.z = f2bf(acc.z); l4.z = f2bf(acc.z - bf2f(h4.z));
    h4.w = f2bf(acc.w); l4.w = f2bf(acc.w - bf2f(h4.w));
    *(ushort4*)&out_hi[(size_t)row * 512 + t4] = h4;
    *(ushort4*)&out_lo[(size_t)row * 512 + t4] = l4;
}

// CSR SpMM, 64 cols: 4 rows per 256-thread block (64 lanes per row), fp32.
__global__ __launch_bounds__(256) void spmm_csr64(
    const int* __restrict__ row_ptr, const int* __restrict__ cols,
    const float* __restrict__ vals, const float* __restrict__ dense,
    float* __restrict__ out)
{
    const int row = blockIdx.x * 4 + (threadIdx.x >> 6);
    const int c = threadIdx.x & 63;
    int e = row_ptr[row];
    const int e1 = row_ptr[row + 1];
    float acc0 = 0.f, acc1 = 0.f;
    for (; e + 2 <= e1; e += 2) {
        acc0 = fmaf(vals[e],     dense[(size_t)cols[e]     * 64 + c], acc0);
        acc1 = fmaf(vals[e + 1], dense[(size_t)cols[e + 1] * 64 + c], acc1);
    }
    if (e < e1) acc0 = fmaf(vals[e], dense[(size_t)cols[e] * 64 + c], acc0);
    out[(size_t)row * 64 + c] = acc0 + acc1;
}

// ---------------------------------------------------------------------------
// Global min/max + normalize
// ---------------------------------------------------------------------------
__global__ __launch_bounds__(256) void minmax_partial(const float* __restrict__ x,
                                                      int n, float* __restrict__ part)
{
    float mn = 3.4e38f, mx = -3.4e38f;
    for (int i = blockIdx.x * 256 + threadIdx.x; i < n; i += gridDim.x * 256) {
        float v = x[i];
        mn = fminf(mn, v); mx = fmaxf(mx, v);
    }
    #pragma unroll
    for (int off = 32; off > 0; off >>= 1) {
        mn = fminf(mn, __shfl_down(mn, off, 64));
        mx = fmaxf(mx, __shfl_down(mx, off, 64));
    }
    __shared__ float smn[4], smx[4];
    if ((threadIdx.x & 63) == 0) { smn[threadIdx.x >> 6] = mn; smx[threadIdx.x >> 6] = mx; }
    __syncthreads();
    if (threadIdx.x == 0) {
        mn = fminf(fminf(smn[0], smn[1]), fminf(smn[2], smn[3]));
        mx = fmaxf(fmaxf(smx[0], smx[1]), fmaxf(smx[2], smx[3]));
        part[blockIdx.x] = mn;
        part[gridDim.x + blockIdx.x] = mx;
    }
}

__global__ __launch_bounds__(256) void minmax_final(const float* __restrict__ part,
                                                    float* __restrict__ mm)
{
    float mn = part[threadIdx.x], mx = part[256 + threadIdx.x];
    #pragma unroll
    for (int off = 32; off > 0; off >>= 1) {
        mn = fminf(mn, __shfl_down(mn, off, 64));
        mx = fmaxf(mx, __shfl_down(mx, off, 64));
    }
    __shared__ float smn[4], smx[4];
    if ((threadIdx.x & 63) == 0) { smn[threadIdx.x >> 6] = mn; smx[threadIdx.x >> 6] = mx; }
    __syncthreads();
    if (threadIdx.x == 0) {
        mm[0] = fminf(fminf(smn[0], smn[1]), fminf(smn[2], smn[3]));
        mm[1] = fmaxf(fmaxf(smx[0], smx[1]), fmaxf(smx[2], smx[3]));
    }
}

__global__ __launch_bounds__(256) void normalize_kernel(float4* __restrict__ x, int n4,
                                                        const float* __restrict__ mm)
{
    int i = blockIdx.x * 256 + threadIdx.x;
    if (i >= n4) return;
    float mn = mm[0];
    float s = 2.0f / (mm[1] - mn);
    float4 v = x[i];
    v.x = fmaf(v.x - mn, s, -1.f);
    v.y = fmaf(v.y - mn, s, -1.f);
    v.z = fmaf(v.z - mn, s, -1.f);
    v.w = fmaf(v.w - mn, s, -1.f);
    x[i] = v;
}

// ---------------------------------------------------------------------------
extern "C" void kernel_launch(void* const* d_in, const int* in_sizes, int n_in,
                              void* d_out, int out_size, void* d_ws, size_t ws_size,
                              hipStream_t stream)
{
    const float* x       = (const float*)d_in[0];
    const int*   adj_row = (const int*)d_in[1];
    const int*   adj_col = (const int*)d_in[2];
    const float* adj_val = (const float*)d_in[3];
    const float* W_org = (const float*)d_in[4];
    const float* b_org = (const float*)d_in[5];
    const float* W_gc1 = (const float*)d_in[6];
    const float* b_gc1 = (const float*)d_in[7];
    const float* W_gc2 = (const float*)d_in[8];
    const float* b_gc2 = (const float*)d_in[9];
    const float* W_l3  = (const float*)d_in[10];
    const float* b_l3  = (const float*)d_in[11];
    const float* W_out = (const float*)d_in[12];
    const float* b_out = (const float*)d_in[13];
    float* out = (float*)d_out;

    // ---- workspace carve-up (256B aligned), ~375 MB total ----
    char* w = (char*)d_ws;
    size_t off = 0;
    auto alloc = [&](size_t bytes) -> void* {
        void* p = w + off;
        off += (bytes + 255) & ~(size_t)255;
        return p;
    };
    unsigned short* g_hi = (unsigned short*)alloc((size_t)N_NODES * H3 * 2); // 76.8 MB
    unsigned short* g_lo = (unsigned short*)alloc((size_t)N_NODES * H3 * 2); // 76.8 MB
    float* h = (float*)alloc((size_t)N_NODES * H2 * 4);                      // 102.4 MB
    // ah pair region; reused for s + as_ after GEMM2 consumes it
    char* region_ah = (char*)alloc((size_t)N_NODES * H2 * 4);                // 102.4 MB
    unsigned short* ah_hi = (unsigned short*)region_ah;
    unsigned short* ah_lo = ah_hi + (size_t)N_NODES * H2;
    float* s   = (float*)region_ah;
    float* as_ = s + (size_t)N_NODES * NCLASS;
    int*   counts  = (int*)alloc((size_t)N_NODES * 4);
    int*   row_ptr = (int*)alloc((size_t)(N_NODES + 1) * 4);
    int*   row_cur = (int*)alloc((size_t)N_NODES * 4);
    int*   cols_s  = (int*)alloc((size_t)N_EDGES * 4);
    float* vals_s  = (float*)alloc((size_t)N_EDGES * 4);
    float* Wco = (float*)alloc((size_t)H3 * NCLASS * 4);
    float* Wlo = (float*)alloc((size_t)H2 * NCLASS * 4);
    unsigned short* WorgT_hi = (unsigned short*)alloc((size_t)H2 * NFEAT * 2);
    unsigned short* WorgT_lo = (unsigned short*)alloc((size_t)H2 * NFEAT * 2);
    unsigned short* Wgc1T_hi = (unsigned short*)alloc((size_t)H3 * H2 * 2);
    unsigned short* Wgc1T_lo = (unsigned short*)alloc((size_t)H3 * H2 * 2);
    unsigned short* WcoT_hi  = (unsigned short*)alloc((size_t)NCLASS * H3 * 2);
    unsigned short* WcoT_lo  = (unsigned short*)alloc((size_t)NCLASS * H3 * 2);
    unsigned short* WloT_hi  = (unsigned short*)alloc((size_t)NCLASS * H2 * 2);
    unsigned short* WloT_lo  = (unsigned short*)alloc((size_t)NCLASS * H2 * 2);
    float* bias_total = (float*)alloc(NCLASS * 4);
    float* part = (float*)alloc(512 * 4);
    float* mm   = (float*)alloc(2 * 4);
    (void)ws_size; (void)n_in; (void)in_sizes; (void)out_size;

    // ---- weight folds + prep + CSR build ----
    hipMemsetAsync(counts, 0, (size_t)N_NODES * 4, stream);
    fold_weights_kernel<<<321, 256, 0, stream>>>(W_gc2, W_l3, W_out, b_gc2, b_l3,
                                                 b_out, Wco, Wlo, bias_total);
    prep_weights_kernel<<<2880, 256, 0, stream>>>(W_org, W_gc1, Wco, Wlo,
        WorgT_hi, WorgT_lo, Wgc1T_hi, Wgc1T_lo, WcoT_hi, WcoT_lo, WloT_hi, WloT_lo);
    hist_kernel<<<N_EDGES / 256, 256, 0, stream>>>(adj_row, counts);
    scan_kernel<<<1, 1024, 0, stream>>>(counts, row_ptr, row_cur, N_NODES);
    scatter_kernel<<<N_EDGES / 256, 256, 0, stream>>>(adj_row, adj_col, adj_val,
                                                      row_cur, cols_s, vals_s);

    const int MB = (N_NODES + 127) / 128;  // 391

    // h = x @ W_org + b_org            [N,512]  (A fp32, write f32)
    gemm_mfma<128, 1, true, false, true><<<MB * 4, 256, 0, stream>>>(
        x, nullptr, nullptr, WorgT_hi, WorgT_lo, b_org, nullptr,
        h, nullptr, nullptr, N_NODES, H2, NFEAT, 4);
    // ah = adj @ h                     [N,512]  (bf16 pair out)
    spmm_csr512_pair<<<N_NODES / 2, 256, 0, stream>>>(row_ptr, cols_s, vals_s, h,
                                                      ah_hi, ah_lo);
    // g = relu(ah @ W_gc1 + b_gc1)     [N,768]  (A pair, write pair)
    gemm_mfma<128, 2, false, true, false><<<MB * 6, 256, 0, stream>>>(
        nullptr, ah_hi, ah_lo, Wgc1T_hi, Wgc1T_lo, b_gc1, nullptr,
        nullptr, g_hi, g_lo, N_NODES, H3, H2, 6);
    // s = g @ Wco                      [N,64]   (A pair, write f32)
    gemm_mfma<64, 0, false, false, true><<<MB, 256, 0, stream>>>(
        nullptr, g_hi, g_lo, WcoT_hi, WcoT_lo, nullptr, nullptr,
        s, nullptr, nullptr, N_NODES, NCLASS, H3, 1);
    // as = adj @ s                     [N,64]
    spmm_csr64<<<N_NODES / 4, 256, 0, stream>>>(row_ptr, cols_s, vals_s, s, as_);
    // out = h @ Wlo + bias_total + 0.5*as   [N,64]  (A fp32, write f32)
    gemm_mfma<64, 3, true, false, true><<<MB, 256, 0, stream>>>(
        h, nullptr, nullptr, WloT_hi, WloT_lo, bias_total, as_,
        out, nullptr, nullptr, N_NODES, NCLASS, H2, 1);

    // ---- global min-max normalize ----
    const int n_out = N_NODES * NCLASS;
    minmax_partial<<<256, 256, 0, stream>>>(out, n_out, part);
    minmax_final<<<1, 256, 0, stream>>>(part, mm);
    normalize_kernel<<<(n_out / 4 + 255) / 256, 256, 0, stream>>>(
        (float4*)out, n_out / 4, mm);
}

// Round 6
// 1362.838 us; speedup vs baseline: 1.5694x; 1.0496x over previous
//
#include <hip/hip_runtime.h>

#define N_NODES 50000
#define N_EDGES 1600000
#define NFEAT   512
#define H2      512
#define H3      768
#define NCLASS  64
// padded edge capacity: every row rounds up to multiple of 8
#define E_CAP   (N_EDGES + 8 * N_NODES)

typedef __attribute__((ext_vector_type(8))) short bf16x8;
typedef __attribute__((ext_vector_type(4))) float f32x4;

// ---------------------------------------------------------------------------
// bf16 split helpers (round-to-nearest-even)
// ---------------------------------------------------------------------------
__device__ __forceinline__ unsigned short f2bf(float f) {
    unsigned u = __builtin_bit_cast(unsigned, f);
    unsigned r = (u + 0x7FFF + ((u >> 16) & 1)) >> 16;
    return (unsigned short)r;
}
__device__ __forceinline__ float bf2f(unsigned short h) {
    unsigned u = ((unsigned)h) << 16;
    return __builtin_bit_cast(float, u);
}

__device__ __forceinline__ void gload_lds16(const void* g, void* l) {
    __builtin_amdgcn_global_load_lds(
        (const __attribute__((address_space(1))) void*)g,
        (__attribute__((address_space(3))) void*)l, 16, 0, 0);
}

// ---------------------------------------------------------------------------
// Weight folding (see round-3 notes): Wco=W_gc2@W_out, Wlo=W_l3@W_out,
// bias_total = b_out + b_l3@W_out + 0.5*b_gc2@W_out
// ---------------------------------------------------------------------------
__global__ __launch_bounds__(256) void fold_weights_kernel(
    const float* __restrict__ Wgc2, const float* __restrict__ Wl3,
    const float* __restrict__ Wout, const float* __restrict__ b_gc2,
    const float* __restrict__ b_l3, const float* __restrict__ b_out,
    float* __restrict__ Wco, float* __restrict__ Wlo, float* __restrict__ bias_total)
{
    const int b = blockIdx.x;
    const int tid = threadIdx.x;
    if (b < 192) {
        int elem = b * 256 + tid;
        int r = elem >> 6, c = elem & 63;
        float s = 0.f;
        for (int k = 0; k < H3; ++k)
            s = fmaf(Wgc2[r * H3 + k], Wout[k * NCLASS + c], s);
        Wco[elem] = s;
    } else if (b < 320) {
        int elem = (b - 192) * 256 + tid;
        int r = elem >> 6, c = elem & 63;
        float s = 0.f;
        for (int k = 0; k < H3; ++k)
            s = fmaf(Wl3[r * H3 + k], Wout[k * NCLASS + c], s);
        Wlo[elem] = s;
    } else {
        if (tid < NCLASS) {
            float s = b_out[tid];
            for (int k = 0; k < H3; ++k)
                s = fmaf(b_l3[k] + 0.5f * b_gc2[k], Wout[k * NCLASS + tid], s);
            bias_total[tid] = s;
        }
    }
}

// ---------------------------------------------------------------------------
// Weight prep: transpose to [N][K] and split into bf16 hi/lo.
// ---------------------------------------------------------------------------
__global__ __launch_bounds__(256) void prep_weights_kernel(
    const float* __restrict__ Worg, const float* __restrict__ Wgc1,
    const float* __restrict__ Wco, const float* __restrict__ Wlo,
    unsigned short* __restrict__ WorgT_hi, unsigned short* __restrict__ WorgT_lo,
    unsigned short* __restrict__ Wgc1T_hi, unsigned short* __restrict__ Wgc1T_lo,
    unsigned short* __restrict__ WcoT_hi,  unsigned short* __restrict__ WcoT_lo,
    unsigned short* __restrict__ WloT_hi,  unsigned short* __restrict__ WloT_lo)
{
    int e = blockIdx.x * 256 + threadIdx.x;
    float v; unsigned short* hi; unsigned short* lo; int idx;
    if (e < 262144) {                       // WorgT [512][512]
        int n = e >> 9, k = e & 511;
        v = Worg[k * H2 + n]; hi = WorgT_hi; lo = WorgT_lo; idx = e;
    } else if (e < 262144 + 393216) {       // Wgc1T [768][512]
        int e2 = e - 262144;
        int n = e2 >> 9, k = e2 & 511;
        v = Wgc1[k * H3 + n]; hi = Wgc1T_hi; lo = Wgc1T_lo; idx = e2;
    } else if (e < 262144 + 393216 + 49152) { // WcoT [64][768]
        int e3 = e - 262144 - 393216;
        int n = e3 / H3, k = e3 % H3;
        v = Wco[k * NCLASS + n]; hi = WcoT_hi; lo = WcoT_lo; idx = e3;
    } else if (e < 262144 + 393216 + 49152 + 32768) { // WloT [64][512]
        int e4 = e - 262144 - 393216 - 49152;
        int n = e4 >> 9, k = e4 & 511;
        v = Wlo[k * NCLASS + n]; hi = WloT_hi; lo = WloT_lo; idx = e4;
    } else return;
    unsigned short hv = f2bf(v);
    hi[idx] = hv;
    lo[idx] = f2bf(v - bf2f(hv));
}

// ---------------------------------------------------------------------------
// CSR build: histogram -> parallel 3-kernel scan (counts rounded to mult. 8)
//            -> scatter (pads remain col=0,val=0 from memset -> exact zeros)
// ---------------------------------------------------------------------------
__global__ __launch_bounds__(256) void hist_kernel(const int* __restrict__ rows,
                                                   int* __restrict__ counts)
{
    int e = blockIdx.x * 256 + threadIdx.x;
    if (e < N_EDGES) atomicAdd(&counts[rows[e]], 1);
}

// block-local exclusive scan of rounded counts; block totals out
__global__ __launch_bounds__(256) void scan_blocks_kernel(
    const int* __restrict__ counts, int* __restrict__ row_ptr,
    int* __restrict__ btot, int n)
{
    __shared__ int wsum[4];
    const int idx = blockIdx.x * 256 + threadIdx.x;
    const int lane = threadIdx.x & 63;
    const int wid  = threadIdx.x >> 6;
    int v = (idx < n) ? ((counts[idx] + 7) & ~7) : 0;   // pad rows to mult of 8
    int x = v;
    #pragma unroll
    for (int off = 1; off < 64; off <<= 1) {
        int y = __shfl_up(x, off, 64);
        if (lane >= off) x += y;
    }
    if (lane == 63) wsum[wid] = x;
    __syncthreads();
    if (threadIdx.x == 0) {
        int s = 0;
        #pragma unroll
        for (int i = 0; i < 4; ++i) { int t = wsum[i]; wsum[i] = s; s += t; }
        btot[blockIdx.x] = s;
    }
    __syncthreads();
    if (idx < n) row_ptr[idx] = x - v + wsum[wid];      // block-local exclusive
}

// exclusive scan of block totals (nb <= 256), total stored at btot[nb]
__global__ __launch_bounds__(256) void scan_tots_kernel(int* __restrict__ btot, int nb)
{
    __shared__ int wsum[4];
    const int tid = threadIdx.x;
    const int lane = tid & 63;
    const int wid  = tid >> 6;
    int v = (tid < nb) ? btot[tid] : 0;
    int x = v;
    #pragma unroll
    for (int off = 1; off < 64; off <<= 1) {
        int y = __shfl_up(x, off, 64);
        if (lane >= off) x += y;
    }
    if (lane == 63) wsum[wid] = x;
    __syncthreads();
    if (tid == 0) {
        int s = 0;
        #pragma unroll
        for (int i = 0; i < 4; ++i) { int t = wsum[i]; wsum[i] = s; s += t; }
    }
    __syncthreads();
    int excl = x - v + wsum[wid];
    if (tid < nb) btot[tid] = excl;
    if (tid == nb - 1) btot[nb] = excl + v;             // grand total
}

__global__ __launch_bounds__(256) void scan_add_kernel(
    const int* __restrict__ btot, int* __restrict__ row_ptr,
    int* __restrict__ row_cur, int n)
{
    int idx = blockIdx.x * 256 + threadIdx.x;
    if (idx < n) {
        int o = row_ptr[idx] + btot[blockIdx.x];
        row_ptr[idx] = o;
        row_cur[idx] = o;
    }
    if (idx == 0) row_ptr[n] = btot[gridDim.x];
}

__global__ __launch_bounds__(256) void scatter_kernel(
    const int* __restrict__ rows, const int* __restrict__ cols,
    const float* __restrict__ vals, int* __restrict__ row_cur,
    int* __restrict__ cols_s, float* __restrict__ vals_s)
{
    int e = blockIdx.x * 256 + threadIdx.x;
    if (e < N_EDGES) {
        int r = rows[e];
        int p = atomicAdd(&row_cur[r], 1);
        cols_s[p] = cols[e];
        vals_s[p] = vals[e];
    }
}

// ---------------------------------------------------------------------------
// MFMA bf16-split-3 GEMM (see round-3/4 notes; unchanged this round)
// ---------------------------------------------------------------------------
template <int BN, int EPI, bool A_F32, bool WPAIR, bool WF32>
__global__ __launch_bounds__(256, 2) void gemm_mfma(
    const float* __restrict__ Af,
    const unsigned short* __restrict__ Ahi, const unsigned short* __restrict__ Alo,
    const unsigned short* __restrict__ Bhi, const unsigned short* __restrict__ Blo,
    const float* __restrict__ bias, const float* __restrict__ extra,
    float* __restrict__ Cf, unsigned short* __restrict__ Chi,
    unsigned short* __restrict__ Clo,
    int M, int N, int K, int NB)
{
    constexpr int WNF = BN / 32;
    constexpr int BF  = BN / 16;
    constexpr int NCH = 16 + 2 * BF;
    __shared__ unsigned short lds[NCH * 512];

    const int tid  = threadIdx.x;
    const int lane = tid & 63;
    const int wid  = tid >> 6;
    const int wr   = wid >> 1, wc = wid & 1;
    const int fr   = lane & 15;
    const int fk   = (lane >> 4) * 8;

    const int nwg = gridDim.x;
    const int u = blockIdx.x;
    const int q = nwg >> 3, r = nwg & 7;
    const int xcd = u & 7, pos = u >> 3;
    const int wg = (xcd < r ? xcd * (q + 1) : r * (q + 1) + (xcd - r) * q) + pos;
    const int m0 = (wg / NB) * 128;
    const int n0 = (wg % NB) * BN;

    f32x4 acc[4][WNF];
    #pragma unroll
    for (int mi = 0; mi < 4; ++mi)
        #pragma unroll
        for (int ni = 0; ni < WNF; ++ni)
            acc[mi][ni] = (f32x4){0.f, 0.f, 0.f, 0.f};

    for (int kt = 0; kt < K; kt += 32) {
        if constexpr (A_F32) {
            #pragma unroll
            for (int sub = wid; sub < 8; sub += 4) {
                int row = m0 + sub * 16 + fr;
                if (row >= M) row = M - 1;
                const float* src = Af + (size_t)row * K + kt + fk;
                float4 p0 = *(const float4*)src;
                float4 p1 = *(const float4*)(src + 4);
                float v[8] = {p0.x, p0.y, p0.z, p0.w, p1.x, p1.y, p1.z, p1.w};
                bf16x8 h8, l8;
                #pragma unroll
                for (int j = 0; j < 8; ++j) {
                    unsigned short hv = f2bf(v[j]);
                    h8[j] = (short)hv;
                    l8[j] = (short)f2bf(v[j] - bf2f(hv));
                }
                *(bf16x8*)&lds[sub * 512 + lane * 8] = h8;
                *(bf16x8*)&lds[(8 + sub) * 512 + lane * 8] = l8;
            }
            for (int ch = 16 + wid; ch < NCH; ch += 4) {
                int bch = ch - 16;
                int sub = bch % BF;
                const unsigned short* base = (bch < BF) ? Bhi : Blo;
                int col = n0 + sub * 16 + fr;
                gload_lds16(base + (size_t)col * K + kt + fk, &lds[ch * 512]);
            }
        } else {
            for (int ch = wid; ch < NCH; ch += 4) {
                const unsigned short* src;
                if (ch < 16) {
                    int sub = ch & 7;
                    int row = m0 + sub * 16 + fr;
                    if (row >= M) row = M - 1;
                    const unsigned short* base = (ch < 8) ? Ahi : Alo;
                    src = base + (size_t)row * K + kt + fk;
                } else {
                    int bch = ch - 16;
                    int sub = bch % BF;
                    const unsigned short* base = (bch < BF) ? Bhi : Blo;
                    int col = n0 + sub * 16 + fr;
                    src = base + (size_t)col * K + kt + fk;
                }
                gload_lds16(src, &lds[ch * 512]);
            }
        }
        __syncthreads();

        bf16x8 ah[4], al[4], bh[WNF], bl[WNF];
        #pragma unroll
        for (int mi = 0; mi < 4; ++mi) {
            int mf = wr * 4 + mi;
            ah[mi] = *(const bf16x8*)&lds[mf * 512 + lane * 8];
            al[mi] = *(const bf16x8*)&lds[(8 + mf) * 512 + lane * 8];
        }
        #pragma unroll
        for (int ni = 0; ni < WNF; ++ni) {
            int nf = wc * WNF + ni;
            bh[ni] = *(const bf16x8*)&lds[(16 + nf) * 512 + lane * 8];
            bl[ni] = *(const bf16x8*)&lds[(16 + BF + nf) * 512 + lane * 8];
        }
        #pragma unroll
        for (int mi = 0; mi < 4; ++mi)
            #pragma unroll
            for (int ni = 0; ni < WNF; ++ni) {
                acc[mi][ni] = __builtin_amdgcn_mfma_f32_16x16x32_bf16(
                    ah[mi], bh[ni], acc[mi][ni], 0, 0, 0);
                acc[mi][ni] = __builtin_amdgcn_mfma_f32_16x16x32_bf16(
                    ah[mi], bl[ni], acc[mi][ni], 0, 0, 0);
                acc[mi][ni] = __builtin_amdgcn_mfma_f32_16x16x32_bf16(
                    al[mi], bh[ni], acc[mi][ni], 0, 0, 0);
            }
        __syncthreads();
    }

    const int r0 = m0 + wr * 64 + (lane >> 4) * 4;
    const int c0 = n0 + wc * (BN / 2) + (lane & 15);
    #pragma unroll
    for (int mi = 0; mi < 4; ++mi)
        #pragma unroll
        for (int ni = 0; ni < WNF; ++ni) {
            int col = c0 + ni * 16;
            float bv = 0.f;
            if constexpr (EPI > 0) bv = bias[col];
            #pragma unroll
            for (int qi = 0; qi < 4; ++qi) {
                int row = r0 + mi * 16 + qi;
                if (row >= M) continue;
                float v = acc[mi][ni][qi] + bv;
                if constexpr (EPI == 2) v = fmaxf(v, 0.f);
                if constexpr (EPI == 3)
                    v = fmaf(0.5f, extra[(size_t)row * N + col], v);
                size_t idx = (size_t)row * N + col;
                if constexpr (WF32) Cf[idx] = v;
                if constexpr (WPAIR) {
                    unsigned short hv = f2bf(v);
                    Chi[idx] = hv;
                    Clo[idx] = f2bf(v - bf2f(hv));
                }
            }
        }
}

// ---------------------------------------------------------------------------
// CSR SpMM, 512 cols: 2 rows / 256-thread block. Rows padded to mult. of 8:
// int4/float4 edge loads, 8 outstanding 16B gathers per lane (MLP test).
// ---------------------------------------------------------------------------
__global__ __launch_bounds__(256) void spmm_csr512_pair(
    const int* __restrict__ row_ptr, const int* __restrict__ cols,
    const float* __restrict__ vals, const float* __restrict__ dense,
    unsigned short* __restrict__ out_hi, unsigned short* __restrict__ out_lo)
{
    const int row = blockIdx.x * 2 + (threadIdx.x >> 7);
    const int t4 = (threadIdx.x & 127) * 4;
    int e = row_ptr[row];
    const int e1 = row_ptr[row + 1];
    float4 acc = make_float4(0.f, 0.f, 0.f, 0.f);
    for (; e < e1; e += 8) {
        int4   ca = *(const int4*)&cols[e];
        int4   cb = *(const int4*)&cols[e + 4];
        float4 va = *(const float4*)&vals[e];
        float4 vb = *(const float4*)&vals[e + 4];
        float4 d0 = *(const float4*)&dense[(size_t)ca.x * 512 + t4];
        float4 d1 = *(const float4*)&dense[(size_t)ca.y * 512 + t4];
        float4 d2 = *(const float4*)&dense[(size_t)ca.z * 512 + t4];
        float4 d3 = *(const float4*)&dense[(size_t)ca.w * 512 + t4];
        float4 d4 = *(const float4*)&dense[(size_t)cb.x * 512 + t4];
        float4 d5 = *(const float4*)&dense[(size_t)cb.y * 512 + t4];
        float4 d6 = *(const float4*)&dense[(size_t)cb.z * 512 + t4];
        float4 d7 = *(const float4*)&dense[(size_t)cb.w * 512 + t4];
        acc.x = fmaf(va.x, d0.x, fmaf(va.y, d1.x, fmaf(va.z, d2.x, fmaf(va.w, d3.x, acc.x))));
        acc.y = fmaf(va.x, d0.y, fmaf(va.y, d1.y, fmaf(va.z, d2.y, fmaf(va.w, d3.y, acc.y))));
        acc.z = fmaf(va.x, d0.z, fmaf(va.y, d1.z, fmaf(va.z, d2.z, fmaf(va.w, d3.z, acc.z))));
        acc.w = fmaf(va.x, d0.w, fmaf(va.y, d1.w, fmaf(va.z, d2.w, fmaf(va.w, d3.w, acc.w))));
        acc.x = fmaf(vb.x, d4.x, fmaf(vb.y, d5.x, fmaf(vb.z, d6.x, fmaf(vb.w, d7.x, acc.x))));
        acc.y = fmaf(vb.x, d4.y, fmaf(vb.y, d5.y, fmaf(vb.z, d6.y, fmaf(vb.w, d7.y, acc.y))));
        acc.z = fmaf(vb.x, d4.z, fmaf(vb.y, d5.z, fmaf(vb.z, d6.z, fmaf(vb.w, d7.z, acc.z))));
        acc.w = fmaf(vb.x, d4.w, fmaf(vb.y, d5.w, fmaf(vb.z, d6.w, fmaf(vb.w, d7.w, acc.w))));
    }
    ushort4 h4, l4;
    h4.x = f2bf(acc.x); l4.x = f2bf(acc.x - bf2f(h4.x));
    h4.y = f2bf(acc.y); l4.y = f2bf(acc.y - bf2f(h4.y));
    h4.z = f2bf(acc.z); l4.z = f2bf(acc.z - bf2f(h4.z));
    h4.w = f2bf(acc.w); l4.w = f2bf(acc.w - bf2f(h4.w));
    *(ushort4*)&out_hi[(size_t)row * 512 + t4] = h4;
    *(ushort4*)&out_lo[(size_t)row * 512 + t4] = l4;
}

// CSR SpMM, 64 cols: 4 rows per 256-thread block; padded rows -> clean 4-unroll
__global__ __launch_bounds__(256) void spmm_csr64(
    const int* __restrict__ row_ptr, const int* __restrict__ cols,
    const float* __restrict__ vals, const float* __restrict__ dense,
    float* __restrict__ out)
{
    const int row = blockIdx.x * 4 + (threadIdx.x >> 6);
    const int c = threadIdx.x & 63;
    int e = row_ptr[row];
    const int e1 = row_ptr[row + 1];
    float a0 = 0.f, a1 = 0.f, a2 = 0.f, a3 = 0.f;
    for (; e < e1; e += 4) {
        int c0 = cols[e], c1 = cols[e + 1], c2 = cols[e + 2], c3 = cols[e + 3];
        float v0 = vals[e], v1 = vals[e + 1], v2 = vals[e + 2], v3 = vals[e + 3];
        a0 = fmaf(v0, dense[(size_t)c0 * 64 + c], a0);
        a1 = fmaf(v1, dense[(size_t)c1 * 64 + c], a1);
        a2 = fmaf(v2, dense[(size_t)c2 * 64 + c], a2);
        a3 = fmaf(v3, dense[(size_t)c3 * 64 + c], a3);
    }
    out[(size_t)row * 64 + c] = (a0 + a1) + (a2 + a3);
}

// ---------------------------------------------------------------------------
// Global min/max + normalize
// ---------------------------------------------------------------------------
__global__ __launch_bounds__(256) void minmax_partial(const float* __restrict__ x,
                                                      int n, float* __restrict__ part)
{
    float mn = 3.4e38f, mx = -3.4e38f;
    for (int i = blockIdx.x * 256 + threadIdx.x; i < n; i += gridDim.x * 256) {
        float v = x[i];
        mn = fminf(mn, v); mx = fmaxf(mx, v);
    }
    #pragma unroll
    for (int off = 32; off > 0; off >>= 1) {
        mn = fminf(mn, __shfl_down(mn, off, 64));
        mx = fmaxf(mx, __shfl_down(mx, off, 64));
    }
    __shared__ float smn[4], smx[4];
    if ((threadIdx.x & 63) == 0) { smn[threadIdx.x >> 6] = mn; smx[threadIdx.x >> 6] = mx; }
    __syncthreads();
    if (threadIdx.x == 0) {
        mn = fminf(fminf(smn[0], smn[1]), fminf(smn[2], smn[3]));
        mx = fmaxf(fmaxf(smx[0], smx[1]), fmaxf(smx[2], smx[3]));
        part[blockIdx.x] = mn;
        part[gridDim.x + blockIdx.x] = mx;
    }
}

__global__ __launch_bounds__(256) void minmax_final(const float* __restrict__ part,
                                                    float* __restrict__ mm)
{
    float mn = part[threadIdx.x], mx = part[256 + threadIdx.x];
    #pragma unroll
    for (int off = 32; off > 0; off >>= 1) {
        mn = fminf(mn, __shfl_down(mn, off, 64));
        mx = fmaxf(mx, __shfl_down(mx, off, 64));
    }
    __shared__ float smn[4], smx[4];
    if ((threadIdx.x & 63) == 0) { smn[threadIdx.x >> 6] = mn; smx[threadIdx.x >> 6] = mx; }
    __syncthreads();
    if (threadIdx.x == 0) {
        mm[0] = fminf(fminf(smn[0], smn[1]), fminf(smn[2], smn[3]));
        mm[1] = fmaxf(fmaxf(smx[0], smx[1]), fmaxf(smx[2], smx[3]));
    }
}

__global__ __launch_bounds__(256) void normalize_kernel(float4* __restrict__ x, int n4,
                                                        const float* __restrict__ mm)
{
    int i = blockIdx.x * 256 + threadIdx.x;
    if (i >= n4) return;
    float mn = mm[0];
    float s = 2.0f / (mm[1] - mn);
    float4 v = x[i];
    v.x = fmaf(v.x - mn, s, -1.f);
    v.y = fmaf(v.y - mn, s, -1.f);
    v.z = fmaf(v.z - mn, s, -1.f);
    v.w = fmaf(v.w - mn, s, -1.f);
    x[i] = v;
}

// ---------------------------------------------------------------------------
extern "C" void kernel_launch(void* const* d_in, const int* in_sizes, int n_in,
                              void* d_out, int out_size, void* d_ws, size_t ws_size,
                              hipStream_t stream)
{
    const float* x       = (const float*)d_in[0];
    const int*   adj_row = (const int*)d_in[1];
    const int*   adj_col = (const int*)d_in[2];
    const float* adj_val = (const float*)d_in[3];
    const float* W_org = (const float*)d_in[4];
    const float* b_org = (const float*)d_in[5];
    const float* W_gc1 = (const float*)d_in[6];
    const float* b_gc1 = (const float*)d_in[7];
    const float* W_gc2 = (const float*)d_in[8];
    const float* b_gc2 = (const float*)d_in[9];
    const float* W_l3  = (const float*)d_in[10];
    const float* b_l3  = (const float*)d_in[11];
    const float* W_out = (const float*)d_in[12];
    const float* b_out = (const float*)d_in[13];
    float* out = (float*)d_out;

    // ---- workspace carve-up (256B aligned), ~381 MB total ----
    char* w = (char*)d_ws;
    size_t off = 0;
    auto alloc = [&](size_t bytes) -> void* {
        void* p = w + off;
        off += (bytes + 255) & ~(size_t)255;
        return p;
    };
    unsigned short* g_hi = (unsigned short*)alloc((size_t)N_NODES * H3 * 2); // 76.8 MB
    unsigned short* g_lo = (unsigned short*)alloc((size_t)N_NODES * H3 * 2); // 76.8 MB
    float* h = (float*)alloc((size_t)N_NODES * H2 * 4);                      // 102.4 MB
    char* region_ah = (char*)alloc((size_t)N_NODES * H2 * 4);                // 102.4 MB
    unsigned short* ah_hi = (unsigned short*)region_ah;
    unsigned short* ah_lo = ah_hi + (size_t)N_NODES * H2;
    float* s   = (float*)region_ah;
    float* as_ = s + (size_t)N_NODES * NCLASS;
    int*   counts  = (int*)alloc((size_t)N_NODES * 4);
    int*   row_ptr = (int*)alloc((size_t)(N_NODES + 1) * 4);
    int*   row_cur = (int*)alloc((size_t)N_NODES * 4);
    int*   btot    = (int*)alloc(256 * 4);
    int*   cols_s  = (int*)alloc((size_t)E_CAP * 4);
    float* vals_s  = (float*)alloc((size_t)E_CAP * 4);
    float* Wco = (float*)alloc((size_t)H3 * NCLASS * 4);
    float* Wlo = (float*)alloc((size_t)H2 * NCLASS * 4);
    unsigned short* WorgT_hi = (unsigned short*)alloc((size_t)H2 * NFEAT * 2);
    unsigned short* WorgT_lo = (unsigned short*)alloc((size_t)H2 * NFEAT * 2);
    unsigned short* Wgc1T_hi = (unsigned short*)alloc((size_t)H3 * H2 * 2);
    unsigned short* Wgc1T_lo = (unsigned short*)alloc((size_t)H3 * H2 * 2);
    unsigned short* WcoT_hi  = (unsigned short*)alloc((size_t)NCLASS * H3 * 2);
    unsigned short* WcoT_lo  = (unsigned short*)alloc((size_t)NCLASS * H3 * 2);
    unsigned short* WloT_hi  = (unsigned short*)alloc((size_t)NCLASS * H2 * 2);
    unsigned short* WloT_lo  = (unsigned short*)alloc((size_t)NCLASS * H2 * 2);
    float* bias_total = (float*)alloc(NCLASS * 4);
    float* part = (float*)alloc(512 * 4);
    float* mm   = (float*)alloc(2 * 4);
    (void)ws_size; (void)n_in; (void)in_sizes; (void)out_size;

    // ---- weight folds + prep + CSR build ----
    hipMemsetAsync(counts, 0, (size_t)N_NODES * 4, stream);
    hipMemsetAsync(cols_s, 0, (size_t)E_CAP * 4, stream);   // pads -> col 0
    hipMemsetAsync(vals_s, 0, (size_t)E_CAP * 4, stream);   // pads -> val 0
    fold_weights_kernel<<<321, 256, 0, stream>>>(W_gc2, W_l3, W_out, b_gc2, b_l3,
                                                 b_out, Wco, Wlo, bias_total);
    prep_weights_kernel<<<2880, 256, 0, stream>>>(W_org, W_gc1, Wco, Wlo,
        WorgT_hi, WorgT_lo, Wgc1T_hi, Wgc1T_lo, WcoT_hi, WcoT_lo, WloT_hi, WloT_lo);
    hist_kernel<<<N_EDGES / 256, 256, 0, stream>>>(adj_row, counts);
    const int NSB = (N_NODES + 255) / 256;   // 196 scan blocks
    scan_blocks_kernel<<<NSB, 256, 0, stream>>>(counts, row_ptr, btot, N_NODES);
    scan_tots_kernel<<<1, 256, 0, stream>>>(btot, NSB);
    scan_add_kernel<<<NSB, 256, 0, stream>>>(btot, row_ptr, row_cur, N_NODES);
    scatter_kernel<<<N_EDGES / 256, 256, 0, stream>>>(adj_row, adj_col, adj_val,
                                                      row_cur, cols_s, vals_s);

    const int MB = (N_NODES + 127) / 128;  // 391

    // h = x @ W_org + b_org            [N,512]  (A fp32, write f32)
    gemm_mfma<128, 1, true, false, true><<<MB * 4, 256, 0, stream>>>(
        x, nullptr, nullptr, WorgT_hi, WorgT_lo, b_org, nullptr,
        h, nullptr, nullptr, N_NODES, H2, NFEAT, 4);
    // ah = adj @ h                     [N,512]  (bf16 pair out)
    spmm_csr512_pair<<<N_NODES / 2, 256, 0, stream>>>(row_ptr, cols_s, vals_s, h,
                                                      ah_hi, ah_lo);
    // g = relu(ah @ W_gc1 + b_gc1)     [N,768]  (A pair, write pair)
    gemm_mfma<128, 2, false, true, false><<<MB * 6, 256, 0, stream>>>(
        nullptr, ah_hi, ah_lo, Wgc1T_hi, Wgc1T_lo, b_gc1, nullptr,
        nullptr, g_hi, g_lo, N_NODES, H3, H2, 6);
    // s = g @ Wco                      [N,64]   (A pair, write f32)
    gemm_mfma<64, 0, false, false, true><<<MB, 256, 0, stream>>>(
        nullptr, g_hi, g_lo, WcoT_hi, WcoT_lo, nullptr, nullptr,
        s, nullptr, nullptr, N_NODES, NCLASS, H3, 1);
    // as = adj @ s                     [N,64]
    spmm_csr64<<<N_NODES / 4, 256, 0, stream>>>(row_ptr, cols_s, vals_s, s, as_);
    // out = h @ Wlo + bias_total + 0.5*as   [N,64]  (A fp32, write f32)
    gemm_mfma<64, 3, true, false, true><<<MB, 256, 0, stream>>>(
        h, nullptr, nullptr, WloT_hi, WloT_lo, bias_total, as_,
        out, nullptr, nullptr, N_NODES, NCLASS, H2, 1);

    // ---- global min-max normalize ----
    const int n_out = N_NODES * NCLASS;
    minmax_partial<<<256, 256, 0, stream>>>(out, n_out, part);
    minmax_final<<<1, 256, 0, stream>>>(part, mm);
    normalize_kernel<<<(n_out / 4 + 255) / 256, 256, 0, stream>>>(
        (float4*)out, n_out / 4, mm);
}

// Round 10
// 1132.609 us; speedup vs baseline: 1.8884x; 1.2033x over previous
//
#include <hip/hip_runtime.h>

#define N_NODES 50000
#define N_EDGES 1600000
#define NFEAT   512
#define H2      512
#define H3      768
#define NCLASS  64
// padded edge capacity: every row rounds up to multiple of 8
#define E_CAP   (N_EDGES + 8 * N_NODES)

typedef __attribute__((ext_vector_type(8))) short bf16x8;
typedef __attribute__((ext_vector_type(4))) float f32x4;
typedef __attribute__((ext_vector_type(8))) _Float16 f16x8;
typedef __attribute__((ext_vector_type(8))) unsigned short u16x8;

// ---------------------------------------------------------------------------
// bf16 split helpers (round-to-nearest-even)
// ---------------------------------------------------------------------------
__device__ __forceinline__ unsigned short f2bf(float f) {
    unsigned u = __builtin_bit_cast(unsigned, f);
    unsigned r = (u + 0x7FFF + ((u >> 16) & 1)) >> 16;
    return (unsigned short)r;
}
__device__ __forceinline__ float bf2f(unsigned short h) {
    unsigned u = ((unsigned)h) << 16;
    return __builtin_bit_cast(float, u);
}

__device__ __forceinline__ void gload_lds16(const void* g, void* l) {
    __builtin_amdgcn_global_load_lds(
        (const __attribute__((address_space(1))) void*)g,
        (__attribute__((address_space(3))) void*)l, 16, 0, 0);
}

// ---------------------------------------------------------------------------
// Weight folding: Wco=W_gc2@W_out, Wlo=W_l3@W_out,
// bias_total = b_out + b_l3@W_out + 0.5*b_gc2@W_out
// ---------------------------------------------------------------------------
__global__ __launch_bounds__(256) void fold_weights_kernel(
    const float* __restrict__ Wgc2, const float* __restrict__ Wl3,
    const float* __restrict__ Wout, const float* __restrict__ b_gc2,
    const float* __restrict__ b_l3, const float* __restrict__ b_out,
    float* __restrict__ Wco, float* __restrict__ Wlo, float* __restrict__ bias_total)
{
    const int b = blockIdx.x;
    const int tid = threadIdx.x;
    if (b < 192) {
        int elem = b * 256 + tid;
        int r = elem >> 6, c = elem & 63;
        float s = 0.f;
        for (int k = 0; k < H3; ++k)
            s = fmaf(Wgc2[r * H3 + k], Wout[k * NCLASS + c], s);
        Wco[elem] = s;
    } else if (b < 320) {
        int elem = (b - 192) * 256 + tid;
        int r = elem >> 6, c = elem & 63;
        float s = 0.f;
        for (int k = 0; k < H3; ++k)
            s = fmaf(Wl3[r * H3 + k], Wout[k * NCLASS + c], s);
        Wlo[elem] = s;
    } else {
        if (tid < NCLASS) {
            float s = b_out[tid];
            for (int k = 0; k < H3; ++k)
                s = fmaf(b_l3[k] + 0.5f * b_gc2[k], Wout[k * NCLASS + tid], s);
            bias_total[tid] = s;
        }
    }
}

// ---------------------------------------------------------------------------
// Weight prep: transpose to [N][K] and split into bf16 hi/lo.
// ---------------------------------------------------------------------------
__global__ __launch_bounds__(256) void prep_weights_kernel(
    const float* __restrict__ Worg, const float* __restrict__ Wgc1,
    const float* __restrict__ Wco, const float* __restrict__ Wlo,
    unsigned short* __restrict__ WorgT_hi, unsigned short* __restrict__ WorgT_lo,
    unsigned short* __restrict__ Wgc1T_hi, unsigned short* __restrict__ Wgc1T_lo,
    unsigned short* __restrict__ WcoT_hi,  unsigned short* __restrict__ WcoT_lo,
    unsigned short* __restrict__ WloT_hi,  unsigned short* __restrict__ WloT_lo)
{
    int e = blockIdx.x * 256 + threadIdx.x;
    float v; unsigned short* hi; unsigned short* lo; int idx;
    if (e < 262144) {                       // WorgT [512][512]
        int n = e >> 9, k = e & 511;
        v = Worg[k * H2 + n]; hi = WorgT_hi; lo = WorgT_lo; idx = e;
    } else if (e < 262144 + 393216) {       // Wgc1T [768][512]
        int e2 = e - 262144;
        int n = e2 >> 9, k = e2 & 511;
        v = Wgc1[k * H3 + n]; hi = Wgc1T_hi; lo = Wgc1T_lo; idx = e2;
    } else if (e < 262144 + 393216 + 49152) { // WcoT [64][768]
        int e3 = e - 262144 - 393216;
        int n = e3 / H3, k = e3 % H3;
        v = Wco[k * NCLASS + n]; hi = WcoT_hi; lo = WcoT_lo; idx = e3;
    } else if (e < 262144 + 393216 + 49152 + 32768) { // WloT [64][512]
        int e4 = e - 262144 - 393216 - 49152;
        int n = e4 >> 9, k = e4 & 511;
        v = Wlo[k * NCLASS + n]; hi = WloT_hi; lo = WloT_lo; idx = e4;
    } else return;
    unsigned short hv = f2bf(v);
    hi[idx] = hv;
    lo[idx] = f2bf(v - bf2f(hv));
}

// ---------------------------------------------------------------------------
// CSR build: histogram -> parallel 3-kernel scan (rows padded to mult. of 8)
//            -> scatter (pads remain col=0,val=0 from memset -> exact zeros)
// ---------------------------------------------------------------------------
__global__ __launch_bounds__(256) void hist_kernel(const int* __restrict__ rows,
                                                   int* __restrict__ counts)
{
    int e = blockIdx.x * 256 + threadIdx.x;
    if (e < N_EDGES) atomicAdd(&counts[rows[e]], 1);
}

__global__ __launch_bounds__(256) void scan_blocks_kernel(
    const int* __restrict__ counts, int* __restrict__ row_ptr,
    int* __restrict__ btot, int n)
{
    __shared__ int wsum[4];
    const int idx = blockIdx.x * 256 + threadIdx.x;
    const int lane = threadIdx.x & 63;
    const int wid  = threadIdx.x >> 6;
    int v = (idx < n) ? ((counts[idx] + 7) & ~7) : 0;
    int x = v;
    #pragma unroll
    for (int off = 1; off < 64; off <<= 1) {
        int y = __shfl_up(x, off, 64);
        if (lane >= off) x += y;
    }
    if (lane == 63) wsum[wid] = x;
    __syncthreads();
    if (threadIdx.x == 0) {
        int s = 0;
        #pragma unroll
        for (int i = 0; i < 4; ++i) { int t = wsum[i]; wsum[i] = s; s += t; }
        btot[blockIdx.x] = s;
    }
    __syncthreads();
    if (idx < n) row_ptr[idx] = x - v + wsum[wid];
}

__global__ __launch_bounds__(256) void scan_tots_kernel(int* __restrict__ btot, int nb)
{
    __shared__ int wsum[4];
    const int tid = threadIdx.x;
    const int lane = tid & 63;
    const int wid  = tid >> 6;
    int v = (tid < nb) ? btot[tid] : 0;
    int x = v;
    #pragma unroll
    for (int off = 1; off < 64; off <<= 1) {
        int y = __shfl_up(x, off, 64);
        if (lane >= off) x += y;
    }
    if (lane == 63) wsum[wid] = x;
    __syncthreads();
    if (tid == 0) {
        int s = 0;
        #pragma unroll
        for (int i = 0; i < 4; ++i) { int t = wsum[i]; wsum[i] = s; s += t; }
    }
    __syncthreads();
    int excl = x - v + wsum[wid];
    if (tid < nb) btot[tid] = excl;
    if (tid == nb - 1) btot[nb] = excl + v;
}

__global__ __launch_bounds__(256) void scan_add_kernel(
    const int* __restrict__ btot, int* __restrict__ row_ptr,
    int* __restrict__ row_cur, int n)
{
    int idx = blockIdx.x * 256 + threadIdx.x;
    if (idx < n) {
        int o = row_ptr[idx] + btot[blockIdx.x];
        row_ptr[idx] = o;
        row_cur[idx] = o;
    }
    if (idx == 0) row_ptr[n] = btot[gridDim.x];
}

__global__ __launch_bounds__(256) void scatter_kernel(
    const int* __restrict__ rows, const int* __restrict__ cols,
    const float* __restrict__ vals, int* __restrict__ row_cur,
    int* __restrict__ cols_s, float* __restrict__ vals_s)
{
    int e = blockIdx.x * 256 + threadIdx.x;
    if (e < N_EDGES) {
        int r = rows[e];
        int p = atomicAdd(&row_cur[r], 1);
        cols_s[p] = cols[e];
        vals_s[p] = vals[e];
    }
}

// ---------------------------------------------------------------------------
// MFMA bf16-split-3 GEMM.
// AMODE: 0 = A bf16 pair, 1 = A fp32 (split in-register), 2 = A fp16 (split)
// WMODE: 0 = write f32, 1 = write bf16 pair, 2 = write fp16
// EPI: 0 none | 1 +bias | 2 +bias,relu | 3 +bias+0.5*extra
// ---------------------------------------------------------------------------
template <int BN, int EPI, int AMODE, int WMODE>
__global__ __launch_bounds__(256, 2) void gemm_mfma(
    const float* __restrict__ Af, const _Float16* __restrict__ Ah16,
    const unsigned short* __restrict__ Ahi, const unsigned short* __restrict__ Alo,
    const unsigned short* __restrict__ Bhi, const unsigned short* __restrict__ Blo,
    const float* __restrict__ bias, const float* __restrict__ extra,
    float* __restrict__ Cf, _Float16* __restrict__ Ch16,
    unsigned short* __restrict__ Chi, unsigned short* __restrict__ Clo,
    int M, int N, int K, int NB)
{
    constexpr int WNF = BN / 32;
    constexpr int BF  = BN / 16;
    constexpr int NCH = 16 + 2 * BF;
    __shared__ unsigned short lds[NCH * 512];

    const int tid  = threadIdx.x;
    const int lane = tid & 63;
    const int wid  = tid >> 6;
    const int wr   = wid >> 1, wc = wid & 1;
    const int fr   = lane & 15;
    const int fk   = (lane >> 4) * 8;

    const int nwg = gridDim.x;
    const int u = blockIdx.x;
    const int q = nwg >> 3, r = nwg & 7;
    const int xcd = u & 7, pos = u >> 3;
    const int wg = (xcd < r ? xcd * (q + 1) : r * (q + 1) + (xcd - r) * q) + pos;
    const int m0 = (wg / NB) * 128;
    const int n0 = (wg % NB) * BN;

    f32x4 acc[4][WNF];
    #pragma unroll
    for (int mi = 0; mi < 4; ++mi)
        #pragma unroll
        for (int ni = 0; ni < WNF; ++ni)
            acc[mi][ni] = (f32x4){0.f, 0.f, 0.f, 0.f};

    for (int kt = 0; kt < K; kt += 32) {
        if constexpr (AMODE != 0) {
            // A: load fp32/fp16, split in-register, ds_write fragment-major
            #pragma unroll
            for (int sub = wid; sub < 8; sub += 4) {
                int row = m0 + sub * 16 + fr;
                if (row >= M) row = M - 1;
                float v[8];
                if constexpr (AMODE == 1) {
                    const float* src = Af + (size_t)row * K + kt + fk;
                    float4 p0 = *(const float4*)src;
                    float4 p1 = *(const float4*)(src + 4);
                    v[0] = p0.x; v[1] = p0.y; v[2] = p0.z; v[3] = p0.w;
                    v[4] = p1.x; v[5] = p1.y; v[6] = p1.z; v[7] = p1.w;
                } else {
                    const _Float16* src = Ah16 + (size_t)row * K + kt + fk;
                    f16x8 p = *(const f16x8*)src;
                    #pragma unroll
                    for (int j = 0; j < 8; ++j) v[j] = (float)p[j];
                }
                bf16x8 h8, l8;
                #pragma unroll
                for (int j = 0; j < 8; ++j) {
                    unsigned short hv = f2bf(v[j]);
                    h8[j] = (short)hv;
                    l8[j] = (short)f2bf(v[j] - bf2f(hv));
                }
                *(bf16x8*)&lds[sub * 512 + lane * 8] = h8;
                *(bf16x8*)&lds[(8 + sub) * 512 + lane * 8] = l8;
            }
            for (int ch = 16 + wid; ch < NCH; ch += 4) {
                int bch = ch - 16;
                int sub = bch % BF;
                const unsigned short* base = (bch < BF) ? Bhi : Blo;
                int col = n0 + sub * 16 + fr;
                gload_lds16(base + (size_t)col * K + kt + fk, &lds[ch * 512]);
            }
        } else {
            for (int ch = wid; ch < NCH; ch += 4) {
                const unsigned short* src;
                if (ch < 16) {
                    int sub = ch & 7;
                    int row = m0 + sub * 16 + fr;
                    if (row >= M) row = M - 1;
                    const unsigned short* base = (ch < 8) ? Ahi : Alo;
                    src = base + (size_t)row * K + kt + fk;
                } else {
                    int bch = ch - 16;
                    int sub = bch % BF;
                    const unsigned short* base = (bch < BF) ? Bhi : Blo;
                    int col = n0 + sub * 16 + fr;
                    src = base + (size_t)col * K + kt + fk;
                }
                gload_lds16(src, &lds[ch * 512]);
            }
        }
        __syncthreads();

        bf16x8 ah[4], al[4], bh[WNF], bl[WNF];
        #pragma unroll
        for (int mi = 0; mi < 4; ++mi) {
            int mf = wr * 4 + mi;
            ah[mi] = *(const bf16x8*)&lds[mf * 512 + lane * 8];
            al[mi] = *(const bf16x8*)&lds[(8 + mf) * 512 + lane * 8];
        }
        #pragma unroll
        for (int ni = 0; ni < WNF; ++ni) {
            int nf = wc * WNF + ni;
            bh[ni] = *(const bf16x8*)&lds[(16 + nf) * 512 + lane * 8];
            bl[ni] = *(const bf16x8*)&lds[(16 + BF + nf) * 512 + lane * 8];
        }
        #pragma unroll
        for (int mi = 0; mi < 4; ++mi)
            #pragma unroll
            for (int ni = 0; ni < WNF; ++ni) {
                acc[mi][ni] = __builtin_amdgcn_mfma_f32_16x16x32_bf16(
                    ah[mi], bh[ni], acc[mi][ni], 0, 0, 0);
                acc[mi][ni] = __builtin_amdgcn_mfma_f32_16x16x32_bf16(
                    ah[mi], bl[ni], acc[mi][ni], 0, 0, 0);
                acc[mi][ni] = __builtin_amdgcn_mfma_f32_16x16x32_bf16(
                    al[mi], bh[ni], acc[mi][ni], 0, 0, 0);
            }
        __syncthreads();
    }

    // epilogue: C/D mapping col=lane&15, row=(lane>>4)*4+reg  [m89/m91]
    const int r0 = m0 + wr * 64 + (lane >> 4) * 4;
    const int c0 = n0 + wc * (BN / 2) + (lane & 15);
    #pragma unroll
    for (int mi = 0; mi < 4; ++mi)
        #pragma unroll
        for (int ni = 0; ni < WNF; ++ni) {
            int col = c0 + ni * 16;
            float bv = 0.f;
            if constexpr (EPI > 0) bv = bias[col];
            #pragma unroll
            for (int qi = 0; qi < 4; ++qi) {
                int row = r0 + mi * 16 + qi;
                if (row >= M) continue;
                float v = acc[mi][ni][qi] + bv;
                if constexpr (EPI == 2) v = fmaxf(v, 0.f);
                if constexpr (EPI == 3)
                    v = fmaf(0.5f, extra[(size_t)row * N + col], v);
                size_t idx = (size_t)row * N + col;
                if constexpr (WMODE == 0) Cf[idx] = v;
                if constexpr (WMODE == 1) {
                    unsigned short hv = f2bf(v);
                    Chi[idx] = hv;
                    Clo[idx] = f2bf(v - bf2f(hv));
                }
                if constexpr (WMODE == 2) Ch16[idx] = (_Float16)v;
            }
        }
}

// ---------------------------------------------------------------------------
// CSR SpMM, 512 cols, fp16 payload: 1 row per 64-lane wave (lane = 8 cols =
// 16B load), 4 rows / 256-block, 8 edges in flight. fp32 accumulate,
// writes bf16 pair. Rows padded to multiple of 8.
// ---------------------------------------------------------------------------
__global__ __launch_bounds__(256) void spmm_csr512_f16(
    const int* __restrict__ row_ptr, const int* __restrict__ cols,
    const float* __restrict__ vals, const _Float16* __restrict__ dense,
    unsigned short* __restrict__ out_hi, unsigned short* __restrict__ out_lo)
{
    const int row = blockIdx.x * 4 + (threadIdx.x >> 6);
    const int c8 = (threadIdx.x & 63) * 8;
    int e = row_ptr[row];
    const int e1 = row_ptr[row + 1];
    float acc[8] = {0.f, 0.f, 0.f, 0.f, 0.f, 0.f, 0.f, 0.f};
    for (; e < e1; e += 8) {
        int4   ca = *(const int4*)&cols[e];
        int4   cb = *(const int4*)&cols[e + 4];
        float4 va = *(const float4*)&vals[e];
        float4 vb = *(const float4*)&vals[e + 4];
        f16x8 d0 = *(const f16x8*)&dense[(size_t)ca.x * 512 + c8];
        f16x8 d1 = *(const f16x8*)&dense[(size_t)ca.y * 512 + c8];
        f16x8 d2 = *(const f16x8*)&dense[(size_t)ca.z * 512 + c8];
        f16x8 d3 = *(const f16x8*)&dense[(size_t)ca.w * 512 + c8];
        f16x8 d4 = *(const f16x8*)&dense[(size_t)cb.x * 512 + c8];
        f16x8 d5 = *(const f16x8*)&dense[(size_t)cb.y * 512 + c8];
        f16x8 d6 = *(const f16x8*)&dense[(size_t)cb.z * 512 + c8];
        f16x8 d7 = *(const f16x8*)&dense[(size_t)cb.w * 512 + c8];
        #pragma unroll
        for (int j = 0; j < 8; ++j) {
            float a = acc[j];
            a = fmaf(va.x, (float)d0[j], a);
            a = fmaf(va.y, (float)d1[j], a);
            a = fmaf(va.z, (float)d2[j], a);
            a = fmaf(va.w, (float)d3[j], a);
            a = fmaf(vb.x, (float)d4[j], a);
            a = fmaf(vb.y, (float)d5[j], a);
            a = fmaf(vb.z, (float)d6[j], a);
            a = fmaf(vb.w, (float)d7[j], a);
            acc[j] = a;
        }
    }
    u16x8 h8, l8;
    #pragma unroll
    for (int j = 0; j < 8; ++j) {
        unsigned short hv = f2bf(acc[j]);
        h8[j] = hv;
        l8[j] = f2bf(acc[j] - bf2f(hv));
    }
    *(u16x8*)&out_hi[(size_t)row * 512 + c8] = h8;
    *(u16x8*)&out_lo[(size_t)row * 512 + c8] = l8;
}

// CSR SpMM, 64 cols: 4 rows per 256-thread block; padded rows -> clean 4-unroll
__global__ __launch_bounds__(256) void spmm_csr64(
    const int* __restrict__ row_ptr, const int* __restrict__ cols,
    const float* __restrict__ vals, const float* __restrict__ dense,
    float* __restrict__ out)
{
    const int row = blockIdx.x * 4 + (threadIdx.x >> 6);
    const int c = threadIdx.x & 63;
    int e = row_ptr[row];
    const int e1 = row_ptr[row + 1];
    float a0 = 0.f, a1 = 0.f, a2 = 0.f, a3 = 0.f;
    for (; e < e1; e += 4) {
        int c0 = cols[e], c1 = cols[e + 1], c2 = cols[e + 2], c3 = cols[e + 3];
        float v0 = vals[e], v1 = vals[e + 1], v2 = vals[e + 2], v3 = vals[e + 3];
        a0 = fmaf(v0, dense[(size_t)c0 * 64 + c], a0);
        a1 = fmaf(v1, dense[(size_t)c1 * 64 + c], a1);
        a2 = fmaf(v2, dense[(size_t)c2 * 64 + c], a2);
        a3 = fmaf(v3, dense[(size_t)c3 * 64 + c], a3);
    }
    out[(size_t)row * 64 + c] = (a0 + a1) + (a2 + a3);
}

// ---------------------------------------------------------------------------
// Global min/max + normalize
// ---------------------------------------------------------------------------
__global__ __launch_bounds__(256) void minmax_partial(const float* __restrict__ x,
                                                      int n, float* __restrict__ part)
{
    float mn = 3.4e38f, mx = -3.4e38f;
    for (int i = blockIdx.x * 256 + threadIdx.x; i < n; i += gridDim.x * 256) {
        float v = x[i];
        mn = fminf(mn, v); mx = fmaxf(mx, v);
    }
    #pragma unroll
    for (int off = 32; off > 0; off >>= 1) {
        mn = fminf(mn, __shfl_down(mn, off, 64));
        mx = fmaxf(mx, __shfl_down(mx, off, 64));
    }
    __shared__ float smn[4], smx[4];
    if ((threadIdx.x & 63) == 0) { smn[threadIdx.x >> 6] = mn; smx[threadIdx.x >> 6] = mx; }
    __syncthreads();
    if (threadIdx.x == 0) {
        mn = fminf(fminf(smn[0], smn[1]), fminf(smn[2], smn[3]));
        mx = fmaxf(fmaxf(smx[0], smx[1]), fmaxf(smx[2], smx[3]));
        part[blockIdx.x] = mn;
        part[gridDim.x + blockIdx.x] = mx;
    }
}

__global__ __launch_bounds__(256) void minmax_final(const float* __restrict__ part,
                                                    float* __restrict__ mm)
{
    float mn = part[threadIdx.x], mx = part[256 + threadIdx.x];
    #pragma unroll
    for (int off = 32; off > 0; off >>= 1) {
        mn = fminf(mn, __shfl_down(mn, off, 64));
        mx = fmaxf(mx, __shfl_down(mx, off, 64));
    }
    __shared__ float smn[4], smx[4];
    if ((threadIdx.x & 63) == 0) { smn[threadIdx.x >> 6] = mn; smx[threadIdx.x >> 6] = mx; }
    __syncthreads();
    if (threadIdx.x == 0) {
        mm[0] = fminf(fminf(smn[0], smn[1]), fminf(smn[2], smn[3]));
        mm[1] = fmaxf(fmaxf(smx[0], smx[1]), fmaxf(smx[2], smx[3]));
    }
}

__global__ __launch_bounds__(256) void normalize_kernel(float4* __restrict__ x, int n4,
                                                        const float* __restrict__ mm)
{
    int i = blockIdx.x * 256 + threadIdx.x;
    if (i >= n4) return;
    float mn = mm[0];
    float s = 2.0f / (mm[1] - mn);
    float4 v = x[i];
    v.x = fmaf(v.x - mn, s, -1.f);
    v.y = fmaf(v.y - mn, s, -1.f);
    v.z = fmaf(v.z - mn, s, -1.f);
    v.w = fmaf(v.w - mn, s, -1.f);
    x[i] = v;
}

// ---------------------------------------------------------------------------
extern "C" void kernel_launch(void* const* d_in, const int* in_sizes, int n_in,
                              void* d_out, int out_size, void* d_ws, size_t ws_size,
                              hipStream_t stream)
{
    const float* x       = (const float*)d_in[0];
    const int*   adj_row = (const int*)d_in[1];
    const int*   adj_col = (const int*)d_in[2];
    const float* adj_val = (const float*)d_in[3];
    const float* W_org = (const float*)d_in[4];
    const float* b_org = (const float*)d_in[5];
    const float* W_gc1 = (const float*)d_in[6];
    const float* b_gc1 = (const float*)d_in[7];
    const float* W_gc2 = (const float*)d_in[8];
    const float* b_gc2 = (const float*)d_in[9];
    const float* W_l3  = (const float*)d_in[10];
    const float* b_l3  = (const float*)d_in[11];
    const float* W_out = (const float*)d_in[12];
    const float* b_out = (const float*)d_in[13];
    float* out = (float*)d_out;

    // ---- workspace carve-up (256B aligned), ~330 MB total ----
    char* w = (char*)d_ws;
    size_t off = 0;
    auto alloc = [&](size_t bytes) -> void* {
        void* p = w + off;
        off += (bytes + 255) & ~(size_t)255;
        return p;
    };
    unsigned short* g_hi = (unsigned short*)alloc((size_t)N_NODES * H3 * 2); // 76.8 MB
    unsigned short* g_lo = (unsigned short*)alloc((size_t)N_NODES * H3 * 2); // 76.8 MB
    _Float16* h16 = (_Float16*)alloc((size_t)N_NODES * H2 * 2);              // 51.2 MB
    char* region_ah = (char*)alloc((size_t)N_NODES * H2 * 4);                // 102.4 MB
    unsigned short* ah_hi = (unsigned short*)region_ah;
    unsigned short* ah_lo = ah_hi + (size_t)N_NODES * H2;
    float* s   = (float*)region_ah;
    float* as_ = s + (size_t)N_NODES * NCLASS;
    int*   counts  = (int*)alloc((size_t)N_NODES * 4);
    int*   row_ptr = (int*)alloc((size_t)(N_NODES + 1) * 4);
    int*   row_cur = (int*)alloc((size_t)N_NODES * 4);
    int*   btot    = (int*)alloc(256 * 4);
    int*   cols_s  = (int*)alloc((size_t)E_CAP * 4);
    float* vals_s  = (float*)alloc((size_t)E_CAP * 4);
    float* Wco = (float*)alloc((size_t)H3 * NCLASS * 4);
    float* Wlo = (float*)alloc((size_t)H2 * NCLASS * 4);
    unsigned short* WorgT_hi = (unsigned short*)alloc((size_t)H2 * NFEAT * 2);
    unsigned short* WorgT_lo = (unsigned short*)alloc((size_t)H2 * NFEAT * 2);
    unsigned short* Wgc1T_hi = (unsigned short*)alloc((size_t)H3 * H2 * 2);
    unsigned short* Wgc1T_lo = (unsigned short*)alloc((size_t)H3 * H2 * 2);
    unsigned short* WcoT_hi  = (unsigned short*)alloc((size_t)NCLASS * H3 * 2);
    unsigned short* WcoT_lo  = (unsigned short*)alloc((size_t)NCLASS * H3 * 2);
    unsigned short* WloT_hi  = (unsigned short*)alloc((size_t)NCLASS * H2 * 2);
    unsigned short* WloT_lo  = (unsigned short*)alloc((size_t)NCLASS * H2 * 2);
    float* bias_total = (float*)alloc(NCLASS * 4);
    float* part = (float*)alloc(512 * 4);
    float* mm   = (float*)alloc(2 * 4);
    (void)ws_size; (void)n_in; (void)in_sizes; (void)out_size;

    // ---- weight folds + prep + CSR build ----
    hipMemsetAsync(counts, 0, (size_t)N_NODES * 4, stream);
    hipMemsetAsync(cols_s, 0, (size_t)E_CAP * 4, stream);   // pads -> col 0
    hipMemsetAsync(vals_s, 0, (size_t)E_CAP * 4, stream);   // pads -> val 0
    fold_weights_kernel<<<321, 256, 0, stream>>>(W_gc2, W_l3, W_out, b_gc2, b_l3,
                                                 b_out, Wco, Wlo, bias_total);
    prep_weights_kernel<<<2880, 256, 0, stream>>>(W_org, W_gc1, Wco, Wlo,
        WorgT_hi, WorgT_lo, Wgc1T_hi, Wgc1T_lo, WcoT_hi, WcoT_lo, WloT_hi, WloT_lo);
    hist_kernel<<<N_EDGES / 256, 256, 0, stream>>>(adj_row, counts);
    const int NSB = (N_NODES + 255) / 256;   // 196 scan blocks
    scan_blocks_kernel<<<NSB, 256, 0, stream>>>(counts, row_ptr, btot, N_NODES);
    scan_tots_kernel<<<1, 256, 0, stream>>>(btot, NSB);
    scan_add_kernel<<<NSB, 256, 0, stream>>>(btot, row_ptr, row_cur, N_NODES);
    scatter_kernel<<<N_EDGES / 256, 256, 0, stream>>>(adj_row, adj_col, adj_val,
                                                      row_cur, cols_s, vals_s);

    const int MB = (N_NODES + 127) / 128;  // 391

    // h16 = fp16(x @ W_org + b_org)    [N,512]  (A fp32, write fp16)
    gemm_mfma<128, 1, 1, 2><<<MB * 4, 256, 0, stream>>>(
        x, nullptr, nullptr, nullptr, WorgT_hi, WorgT_lo, b_org, nullptr,
        nullptr, h16, nullptr, nullptr, N_NODES, H2, NFEAT, 4);
    // ah = adj @ h16                   [N,512]  (fp16 gather, bf16 pair out)
    spmm_csr512_f16<<<N_NODES / 4, 256, 0, stream>>>(row_ptr, cols_s, vals_s, h16,
                                                     ah_hi, ah_lo);
    // g = relu(ah @ W_gc1 + b_gc1)     [N,768]  (A pair, write pair)
    gemm_mfma<128, 2, 0, 1><<<MB * 6, 256, 0, stream>>>(
        nullptr, nullptr, ah_hi, ah_lo, Wgc1T_hi, Wgc1T_lo, b_gc1, nullptr,
        nullptr, nullptr, g_hi, g_lo, N_NODES, H3, H2, 6);
    // s = g @ Wco                      [N,64]   (A pair, write f32)
    gemm_mfma<64, 0, 0, 0><<<MB, 256, 0, stream>>>(
        nullptr, nullptr, g_hi, g_lo, WcoT_hi, WcoT_lo, nullptr, nullptr,
        s, nullptr, nullptr, nullptr, N_NODES, NCLASS, H3, 1);
    // as = adj @ s                     [N,64]
    spmm_csr64<<<N_NODES / 4, 256, 0, stream>>>(row_ptr, cols_s, vals_s, s, as_);
    // out = h16 @ Wlo + bias_total + 0.5*as   [N,64]  (A fp16, write f32)
    gemm_mfma<64, 3, 2, 0><<<MB, 256, 0, stream>>>(
        nullptr, h16, nullptr, nullptr, WloT_hi, WloT_lo, bias_total, as_,
        out, nullptr, nullptr, nullptr, N_NODES, NCLASS, H2, 1);

    // ---- global min-max normalize ----
    const int n_out = N_NODES * NCLASS;
    minmax_partial<<<256, 256, 0, stream>>>(out, n_out, part);
    minmax_final<<<1, 256, 0, stream>>>(part, mm);
    normalize_kernel<<<(n_out / 4 + 255) / 256, 256, 0, stream>>>(
        (float4*)out, n_out / 4, mm);
}

// Round 11
// 917.461 us; speedup vs baseline: 2.3312x; 1.2345x over previous
//
#include <hip/hip_runtime.h>

#define N_NODES 50000
#define N_EDGES 1600000
#define NFEAT   512
#define H2      512
#define H3      768
#define NCLASS  64
// padded edge capacity: every row rounds up to multiple of 8
#define E_CAP   (N_EDGES + 8 * N_NODES)

typedef __attribute__((ext_vector_type(4))) float f32x4;
typedef __attribute__((ext_vector_type(8))) _Float16 f16x8;

__device__ __forceinline__ void gload_lds16(const void* g, void* l) {
    __builtin_amdgcn_global_load_lds(
        (const __attribute__((address_space(1))) void*)g,
        (__attribute__((address_space(3))) void*)l, 16, 0, 0);
}

// ---------------------------------------------------------------------------
// Weight folding (fp32): Wco=W_gc2@W_out, Wlo=W_l3@W_out,
// bias_total = b_out + b_l3@W_out + 0.5*b_gc2@W_out
// ---------------------------------------------------------------------------
__global__ __launch_bounds__(256) void fold_weights_kernel(
    const float* __restrict__ Wgc2, const float* __restrict__ Wl3,
    const float* __restrict__ Wout, const float* __restrict__ b_gc2,
    const float* __restrict__ b_l3, const float* __restrict__ b_out,
    float* __restrict__ Wco, float* __restrict__ Wlo, float* __restrict__ bias_total)
{
    const int b = blockIdx.x;
    const int tid = threadIdx.x;
    if (b < 192) {
        int elem = b * 256 + tid;
        int r = elem >> 6, c = elem & 63;
        float s = 0.f;
        for (int k = 0; k < H3; ++k)
            s = fmaf(Wgc2[r * H3 + k], Wout[k * NCLASS + c], s);
        Wco[elem] = s;
    } else if (b < 320) {
        int elem = (b - 192) * 256 + tid;
        int r = elem >> 6, c = elem & 63;
        float s = 0.f;
        for (int k = 0; k < H3; ++k)
            s = fmaf(Wl3[r * H3 + k], Wout[k * NCLASS + c], s);
        Wlo[elem] = s;
    } else {
        if (tid < NCLASS) {
            float s = b_out[tid];
            for (int k = 0; k < H3; ++k)
                s = fmaf(b_l3[k] + 0.5f * b_gc2[k], Wout[k * NCLASS + tid], s);
            bias_total[tid] = s;
        }
    }
}

// ---------------------------------------------------------------------------
// Weight prep: transpose to [N][K] fp16.
//   WorgT [512][512], Wgc1T [768][512], WcoT [64][768], WloT [64][512]
// ---------------------------------------------------------------------------
__global__ __launch_bounds__(256) void prep_weights_f16(
    const float* __restrict__ Worg, const float* __restrict__ Wgc1,
    const float* __restrict__ Wco, const float* __restrict__ Wlo,
    _Float16* __restrict__ WorgT, _Float16* __restrict__ Wgc1T,
    _Float16* __restrict__ WcoT,  _Float16* __restrict__ WloT)
{
    int e = blockIdx.x * 256 + threadIdx.x;
    if (e < 262144) {                       // WorgT [512][512]
        int n = e >> 9, k = e & 511;
        WorgT[e] = (_Float16)Worg[k * H2 + n];
    } else if (e < 262144 + 393216) {       // Wgc1T [768][512]
        int e2 = e - 262144;
        int n = e2 >> 9, k = e2 & 511;
        Wgc1T[e2] = (_Float16)Wgc1[k * H3 + n];
    } else if (e < 262144 + 393216 + 49152) { // WcoT [64][768]
        int e3 = e - 262144 - 393216;
        int n = e3 / H3, k = e3 % H3;
        WcoT[e3] = (_Float16)Wco[k * NCLASS + n];
    } else if (e < 262144 + 393216 + 49152 + 32768) { // WloT [64][512]
        int e4 = e - 262144 - 393216 - 49152;
        int n = e4 >> 9, k = e4 & 511;
        WloT[e4] = (_Float16)Wlo[k * NCLASS + n];
    }
}

// x (fp32) -> x16 (fp16), 8 elems/thread
__global__ __launch_bounds__(256) void convert_x_kernel(
    const float* __restrict__ x, _Float16* __restrict__ x16, int n8)
{
    int i = blockIdx.x * 256 + threadIdx.x;
    if (i >= n8) return;
    const float4* src = (const float4*)&x[i * 8];
    float4 a = src[0], b = src[1];
    f16x8 o;
    o[0] = (_Float16)a.x; o[1] = (_Float16)a.y;
    o[2] = (_Float16)a.z; o[3] = (_Float16)a.w;
    o[4] = (_Float16)b.x; o[5] = (_Float16)b.y;
    o[6] = (_Float16)b.z; o[7] = (_Float16)b.w;
    *(f16x8*)&x16[i * 8] = o;
}

// ---------------------------------------------------------------------------
// CSR build: histogram -> parallel 3-kernel scan (rows padded to mult. of 8)
//            -> scatter (pads remain col=0,val=0 from memset -> exact zeros)
// ---------------------------------------------------------------------------
__global__ __launch_bounds__(256) void hist_kernel(const int* __restrict__ rows,
                                                   int* __restrict__ counts)
{
    int e = blockIdx.x * 256 + threadIdx.x;
    if (e < N_EDGES) atomicAdd(&counts[rows[e]], 1);
}

__global__ __launch_bounds__(256) void scan_blocks_kernel(
    const int* __restrict__ counts, int* __restrict__ row_ptr,
    int* __restrict__ btot, int n)
{
    __shared__ int wsum[4];
    const int idx = blockIdx.x * 256 + threadIdx.x;
    const int lane = threadIdx.x & 63;
    const int wid  = threadIdx.x >> 6;
    int v = (idx < n) ? ((counts[idx] + 7) & ~7) : 0;
    int x = v;
    #pragma unroll
    for (int off = 1; off < 64; off <<= 1) {
        int y = __shfl_up(x, off, 64);
        if (lane >= off) x += y;
    }
    if (lane == 63) wsum[wid] = x;
    __syncthreads();
    if (threadIdx.x == 0) {
        int s = 0;
        #pragma unroll
        for (int i = 0; i < 4; ++i) { int t = wsum[i]; wsum[i] = s; s += t; }
        btot[blockIdx.x] = s;
    }
    __syncthreads();
    if (idx < n) row_ptr[idx] = x - v + wsum[wid];
}

__global__ __launch_bounds__(256) void scan_tots_kernel(int* __restrict__ btot, int nb)
{
    __shared__ int wsum[4];
    const int tid = threadIdx.x;
    const int lane = tid & 63;
    const int wid  = tid >> 6;
    int v = (tid < nb) ? btot[tid] : 0;
    int x = v;
    #pragma unroll
    for (int off = 1; off < 64; off <<= 1) {
        int y = __shfl_up(x, off, 64);
        if (lane >= off) x += y;
    }
    if (lane == 63) wsum[wid] = x;
    __syncthreads();
    if (tid == 0) {
        int s = 0;
        #pragma unroll
        for (int i = 0; i < 4; ++i) { int t = wsum[i]; wsum[i] = s; s += t; }
    }
    __syncthreads();
    int excl = x - v + wsum[wid];
    if (tid < nb) btot[tid] = excl;
    if (tid == nb - 1) btot[nb] = excl + v;
}

__global__ __launch_bounds__(256) void scan_add_kernel(
    const int* __restrict__ btot, int* __restrict__ row_ptr,
    int* __restrict__ row_cur, int n)
{
    int idx = blockIdx.x * 256 + threadIdx.x;
    if (idx < n) {
        int o = row_ptr[idx] + btot[blockIdx.x];
        row_ptr[idx] = o;
        row_cur[idx] = o;
    }
    if (idx == 0) row_ptr[n] = btot[gridDim.x];
}

__global__ __launch_bounds__(256) void scatter_kernel(
    const int* __restrict__ rows, const int* __restrict__ cols,
    const float* __restrict__ vals, int* __restrict__ row_cur,
    int* __restrict__ cols_s, float* __restrict__ vals_s)
{
    int e = blockIdx.x * 256 + threadIdx.x;
    if (e < N_EDGES) {
        int r = rows[e];
        int p = atomicAdd(&row_cur[r], 1);
        cols_s[p] = cols[e];
        vals_s[p] = vals[e];
    }
}

// ---------------------------------------------------------------------------
// fp16 MFMA GEMM.  C[M,N] = A[M,K] @ B[K,N] (+ epilogue)
// A fp16 [M][K]; B fp16 transposed [N][K]. Single mfma_f32_16x16x32_f16 per
// fragment pair (fp32 accumulate). BM=128, 4 waves (2x2), frags 16x16x32.
// LDS 1KB chunks fragment-major: [A 8][B BN/16]. Both A and B staged with the
// identical (fr,fk) lane mapping -> layout-immune dot product.
// WMODE: 0 = write f32, 2 = write fp16
// EPI: 0 none | 1 +bias | 2 +bias,relu | 3 +bias+0.5*extra
// ---------------------------------------------------------------------------
template <int BN, int EPI, int WMODE>
__global__ __launch_bounds__(256, 2) void gemm_f16(
    const _Float16* __restrict__ A16, const _Float16* __restrict__ B16,
    const float* __restrict__ bias, const float* __restrict__ extra,
    float* __restrict__ Cf, _Float16* __restrict__ Ch16,
    int M, int N, int K, int NB)
{
    constexpr int WNF = BN / 32;          // n-frags per wave
    constexpr int BF  = BN / 16;          // B chunks
    constexpr int NCH = 8 + BF;           // 1KB LDS chunks
    __shared__ _Float16 lds[NCH * 512];

    const int tid  = threadIdx.x;
    const int lane = tid & 63;
    const int wid  = tid >> 6;
    const int wr   = wid >> 1, wc = wid & 1;
    const int fr   = lane & 15;
    const int fk   = (lane >> 4) * 8;

    // bijective XCD-chunked block swizzle (m204)
    const int nwg = gridDim.x;
    const int u = blockIdx.x;
    const int q = nwg >> 3, r = nwg & 7;
    const int xcd = u & 7, pos = u >> 3;
    const int wg = (xcd < r ? xcd * (q + 1) : r * (q + 1) + (xcd - r) * q) + pos;
    const int m0 = (wg / NB) * 128;
    const int n0 = (wg % NB) * BN;

    f32x4 acc[4][WNF];
    #pragma unroll
    for (int mi = 0; mi < 4; ++mi)
        #pragma unroll
        for (int ni = 0; ni < WNF; ++ni)
            acc[mi][ni] = (f32x4){0.f, 0.f, 0.f, 0.f};

    for (int kt = 0; kt < K; kt += 32) {
        // stage: A chunks 0..7, B chunks 8..NCH-1 (wave-uniform LDS dest)
        for (int ch = wid; ch < NCH; ch += 4) {
            const _Float16* src;
            if (ch < 8) {
                int row = m0 + ch * 16 + fr;
                if (row >= M) row = M - 1;
                src = A16 + (size_t)row * K + kt + fk;
            } else {
                int col = n0 + (ch - 8) * 16 + fr;
                src = B16 + (size_t)col * K + kt + fk;
            }
            gload_lds16(src, &lds[ch * 512]);
        }
        __syncthreads();

        f16x8 a[4], b[WNF];
        #pragma unroll
        for (int mi = 0; mi < 4; ++mi)
            a[mi] = *(const f16x8*)&lds[(wr * 4 + mi) * 512 + lane * 8];
        #pragma unroll
        for (int ni = 0; ni < WNF; ++ni)
            b[ni] = *(const f16x8*)&lds[(8 + wc * WNF + ni) * 512 + lane * 8];
        #pragma unroll
        for (int mi = 0; mi < 4; ++mi)
            #pragma unroll
            for (int ni = 0; ni < WNF; ++ni)
                acc[mi][ni] = __builtin_amdgcn_mfma_f32_16x16x32_f16(
                    a[mi], b[ni], acc[mi][ni], 0, 0, 0);
        __syncthreads();
    }

    // epilogue: C/D mapping col=lane&15, row=(lane>>4)*4+reg  [m89/m91]
    const int r0 = m0 + wr * 64 + (lane >> 4) * 4;
    const int c0 = n0 + wc * (BN / 2) + (lane & 15);
    #pragma unroll
    for (int mi = 0; mi < 4; ++mi)
        #pragma unroll
        for (int ni = 0; ni < WNF; ++ni) {
            int col = c0 + ni * 16;
            float bv = 0.f;
            if constexpr (EPI > 0) bv = bias[col];
            #pragma unroll
            for (int qi = 0; qi < 4; ++qi) {
                int row = r0 + mi * 16 + qi;
                if (row >= M) continue;
                float v = acc[mi][ni][qi] + bv;
                if constexpr (EPI == 2) v = fmaxf(v, 0.f);
                if constexpr (EPI == 3)
                    v = fmaf(0.5f, extra[(size_t)row * N + col], v);
                size_t idx = (size_t)row * N + col;
                if constexpr (WMODE == 0) Cf[idx] = v;
                if constexpr (WMODE == 2) Ch16[idx] = (_Float16)v;
            }
        }
}

// ---------------------------------------------------------------------------
// CSR SpMM, 512 cols, fp16 payload: 1 row per 64-lane wave (lane = 8 cols =
// 16B load), 4 rows / 256-block, 8 edges in flight, fp32 accumulate,
// writes fp16. Rows padded to multiple of 8.
// ---------------------------------------------------------------------------
__global__ __launch_bounds__(256) void spmm_csr512_f16(
    const int* __restrict__ row_ptr, const int* __restrict__ cols,
    const float* __restrict__ vals, const _Float16* __restrict__ dense,
    _Float16* __restrict__ out16)
{
    const int row = blockIdx.x * 4 + (threadIdx.x >> 6);
    const int c8 = (threadIdx.x & 63) * 8;
    int e = row_ptr[row];
    const int e1 = row_ptr[row + 1];
    float acc[8] = {0.f, 0.f, 0.f, 0.f, 0.f, 0.f, 0.f, 0.f};
    for (; e < e1; e += 8) {
        int4   ca = *(const int4*)&cols[e];
        int4   cb = *(const int4*)&cols[e + 4];
        float4 va = *(const float4*)&vals[e];
        float4 vb = *(const float4*)&vals[e + 4];
        f16x8 d0 = *(const f16x8*)&dense[(size_t)ca.x * 512 + c8];
        f16x8 d1 = *(const f16x8*)&dense[(size_t)ca.y * 512 + c8];
        f16x8 d2 = *(const f16x8*)&dense[(size_t)ca.z * 512 + c8];
        f16x8 d3 = *(const f16x8*)&dense[(size_t)ca.w * 512 + c8];
        f16x8 d4 = *(const f16x8*)&dense[(size_t)cb.x * 512 + c8];
        f16x8 d5 = *(const f16x8*)&dense[(size_t)cb.y * 512 + c8];
        f16x8 d6 = *(const f16x8*)&dense[(size_t)cb.z * 512 + c8];
        f16x8 d7 = *(const f16x8*)&dense[(size_t)cb.w * 512 + c8];
        #pragma unroll
        for (int j = 0; j < 8; ++j) {
            float a = acc[j];
            a = fmaf(va.x, (float)d0[j], a);
            a = fmaf(va.y, (float)d1[j], a);
            a = fmaf(va.z, (float)d2[j], a);
            a = fmaf(va.w, (float)d3[j], a);
            a = fmaf(vb.x, (float)d4[j], a);
            a = fmaf(vb.y, (float)d5[j], a);
            a = fmaf(vb.z, (float)d6[j], a);
            a = fmaf(vb.w, (float)d7[j], a);
            acc[j] = a;
        }
    }
    f16x8 o;
    #pragma unroll
    for (int j = 0; j < 8; ++j) o[j] = (_Float16)acc[j];
    *(f16x8*)&out16[(size_t)row * 512 + c8] = o;
}

// CSR SpMM, 64 cols, fp16 payload: 4 rows per 256-thread block, fp32 out.
__global__ __launch_bounds__(256) void spmm_csr64_f16(
    const int* __restrict__ row_ptr, const int* __restrict__ cols,
    const float* __restrict__ vals, const _Float16* __restrict__ dense,
    float* __restrict__ out)
{
    const int row = blockIdx.x * 4 + (threadIdx.x >> 6);
    const int c = threadIdx.x & 63;
    int e = row_ptr[row];
    const int e1 = row_ptr[row + 1];
    float a0 = 0.f, a1 = 0.f, a2 = 0.f, a3 = 0.f;
    for (; e < e1; e += 4) {
        int c0 = cols[e], c1 = cols[e + 1], c2 = cols[e + 2], c3 = cols[e + 3];
        float v0 = vals[e], v1 = vals[e + 1], v2 = vals[e + 2], v3 = vals[e + 3];
        a0 = fmaf(v0, (float)dense[(size_t)c0 * 64 + c], a0);
        a1 = fmaf(v1, (float)dense[(size_t)c1 * 64 + c], a1);
        a2 = fmaf(v2, (float)dense[(size_t)c2 * 64 + c], a2);
        a3 = fmaf(v3, (float)dense[(size_t)c3 * 64 + c], a3);
    }
    out[(size_t)row * 64 + c] = (a0 + a1) + (a2 + a3);
}

// ---------------------------------------------------------------------------
// Global min/max + normalize
// ---------------------------------------------------------------------------
__global__ __launch_bounds__(256) void minmax_partial(const float* __restrict__ x,
                                                      int n, float* __restrict__ part)
{
    float mn = 3.4e38f, mx = -3.4e38f;
    for (int i = blockIdx.x * 256 + threadIdx.x; i < n; i += gridDim.x * 256) {
        float v = x[i];
        mn = fminf(mn, v); mx = fmaxf(mx, v);
    }
    #pragma unroll
    for (int off = 32; off > 0; off >>= 1) {
        mn = fminf(mn, __shfl_down(mn, off, 64));
        mx = fmaxf(mx, __shfl_down(mx, off, 64));
    }
    __shared__ float smn[4], smx[4];
    if ((threadIdx.x & 63) == 0) { smn[threadIdx.x >> 6] = mn; smx[threadIdx.x >> 6] = mx; }
    __syncthreads();
    if (threadIdx.x == 0) {
        mn = fminf(fminf(smn[0], smn[1]), fminf(smn[2], smn[3]));
        mx = fmaxf(fmaxf(smx[0], smx[1]), fmaxf(smx[2], smx[3]));
        part[blockIdx.x] = mn;
        part[gridDim.x + blockIdx.x] = mx;
    }
}

__global__ __launch_bounds__(256) void minmax_final(const float* __restrict__ part,
                                                    float* __restrict__ mm)
{
    float mn = part[threadIdx.x], mx = part[256 + threadIdx.x];
    #pragma unroll
    for (int off = 32; off > 0; off >>= 1) {
        mn = fminf(mn, __shfl_down(mn, off, 64));
        mx = fmaxf(mx, __shfl_down(mx, off, 64));
    }
    __shared__ float smn[4], smx[4];
    if ((threadIdx.x & 63) == 0) { smn[threadIdx.x >> 6] = mn; smx[threadIdx.x >> 6] = mx; }
    __syncthreads();
    if (threadIdx.x == 0) {
        mm[0] = fminf(fminf(smn[0], smn[1]), fminf(smn[2], smn[3]));
        mm[1] = fmaxf(fmaxf(smx[0], smx[1]), fmaxf(smx[2], smx[3]));
    }
}

__global__ __launch_bounds__(256) void normalize_kernel(float4* __restrict__ x, int n4,
                                                        const float* __restrict__ mm)
{
    int i = blockIdx.x * 256 + threadIdx.x;
    if (i >= n4) return;
    float mn = mm[0];
    float s = 2.0f / (mm[1] - mn);
    float4 v = x[i];
    v.x = fmaf(v.x - mn, s, -1.f);
    v.y = fmaf(v.y - mn, s, -1.f);
    v.z = fmaf(v.z - mn, s, -1.f);
    v.w = fmaf(v.w - mn, s, -1.f);
    x[i] = v;
}

// ---------------------------------------------------------------------------
extern "C" void kernel_launch(void* const* d_in, const int* in_sizes, int n_in,
                              void* d_out, int out_size, void* d_ws, size_t ws_size,
                              hipStream_t stream)
{
    const float* x       = (const float*)d_in[0];
    const int*   adj_row = (const int*)d_in[1];
    const int*   adj_col = (const int*)d_in[2];
    const float* adj_val = (const float*)d_in[3];
    const float* W_org = (const float*)d_in[4];
    const float* b_org = (const float*)d_in[5];
    const float* W_gc1 = (const float*)d_in[6];
    const float* b_gc1 = (const float*)d_in[7];
    const float* W_gc2 = (const float*)d_in[8];
    const float* b_gc2 = (const float*)d_in[9];
    const float* W_l3  = (const float*)d_in[10];
    const float* b_l3  = (const float*)d_in[11];
    const float* W_out = (const float*)d_in[12];
    const float* b_out = (const float*)d_in[13];
    float* out = (float*)d_out;

    // ---- workspace carve-up (256B aligned), ~290 MB total ----
    char* w = (char*)d_ws;
    size_t off = 0;
    auto alloc = [&](size_t bytes) -> void* {
        void* p = w + off;
        off += (bytes + 255) & ~(size_t)255;
        return p;
    };
    _Float16* g16  = (_Float16*)alloc((size_t)N_NODES * H3 * 2);   // 76.8 MB
    _Float16* h16  = (_Float16*)alloc((size_t)N_NODES * H2 * 2);   // 51.2 MB
    _Float16* ah16 = (_Float16*)alloc((size_t)N_NODES * H2 * 2);   // 51.2 MB
    _Float16* x16  = (_Float16*)alloc((size_t)N_NODES * NFEAT * 2);// 51.2 MB
    _Float16* s16  = (_Float16*)alloc((size_t)N_NODES * NCLASS * 2);// 6.4 MB
    float*    as_  = (float*)alloc((size_t)N_NODES * NCLASS * 4);  // 12.8 MB
    int*   counts  = (int*)alloc((size_t)N_NODES * 4);
    int*   row_ptr = (int*)alloc((size_t)(N_NODES + 1) * 4);
    int*   row_cur = (int*)alloc((size_t)N_NODES * 4);
    int*   btot    = (int*)alloc(256 * 4);
    int*   cols_s  = (int*)alloc((size_t)E_CAP * 4);
    float* vals_s  = (float*)alloc((size_t)E_CAP * 4);
    float* Wco = (float*)alloc((size_t)H3 * NCLASS * 4);
    float* Wlo = (float*)alloc((size_t)H2 * NCLASS * 4);
    _Float16* WorgT = (_Float16*)alloc((size_t)H2 * NFEAT * 2);
    _Float16* Wgc1T = (_Float16*)alloc((size_t)H3 * H2 * 2);
    _Float16* WcoT  = (_Float16*)alloc((size_t)NCLASS * H3 * 2);
    _Float16* WloT  = (_Float16*)alloc((size_t)NCLASS * H2 * 2);
    float* bias_total = (float*)alloc(NCLASS * 4);
    float* part = (float*)alloc(512 * 4);
    float* mm   = (float*)alloc(2 * 4);
    (void)ws_size; (void)n_in; (void)in_sizes; (void)out_size;

    // ---- weight folds + prep + CSR build ----
    hipMemsetAsync(counts, 0, (size_t)N_NODES * 4, stream);
    hipMemsetAsync(cols_s, 0, (size_t)E_CAP * 4, stream);   // pads -> col 0
    hipMemsetAsync(vals_s, 0, (size_t)E_CAP * 4, stream);   // pads -> val 0
    fold_weights_kernel<<<321, 256, 0, stream>>>(W_gc2, W_l3, W_out, b_gc2, b_l3,
                                                 b_out, Wco, Wlo, bias_total);
    prep_weights_f16<<<2880, 256, 0, stream>>>(W_org, W_gc1, Wco, Wlo,
                                               WorgT, Wgc1T, WcoT, WloT);
    convert_x_kernel<<<(N_NODES * NFEAT / 8 + 255) / 256, 256, 0, stream>>>(
        x, x16, N_NODES * NFEAT / 8);
    hist_kernel<<<N_EDGES / 256, 256, 0, stream>>>(adj_row, counts);
    const int NSB = (N_NODES + 255) / 256;   // 196 scan blocks
    scan_blocks_kernel<<<NSB, 256, 0, stream>>>(counts, row_ptr, btot, N_NODES);
    scan_tots_kernel<<<1, 256, 0, stream>>>(btot, NSB);
    scan_add_kernel<<<NSB, 256, 0, stream>>>(btot, row_ptr, row_cur, N_NODES);
    scatter_kernel<<<N_EDGES / 256, 256, 0, stream>>>(adj_row, adj_col, adj_val,
                                                      row_cur, cols_s, vals_s);

    const int MB = (N_NODES + 127) / 128;  // 391

    // h16 = fp16(x @ W_org + b_org)    [N,512]
    gemm_f16<128, 1, 2><<<MB * 4, 256, 0, stream>>>(
        x16, WorgT, b_org, nullptr, nullptr, h16, N_NODES, H2, NFEAT, 4);
    // ah16 = adj @ h16                 [N,512]
    spmm_csr512_f16<<<N_NODES / 4, 256, 0, stream>>>(row_ptr, cols_s, vals_s,
                                                     h16, ah16);
    // g16 = relu(ah16 @ W_gc1 + b_gc1) [N,768]
    gemm_f16<128, 2, 2><<<MB * 6, 256, 0, stream>>>(
        ah16, Wgc1T, b_gc1, nullptr, nullptr, g16, N_NODES, H3, H2, 6);
    // s16 = g16 @ Wco                  [N,64]
    gemm_f16<64, 0, 2><<<MB, 256, 0, stream>>>(
        g16, WcoT, nullptr, nullptr, nullptr, s16, N_NODES, NCLASS, H3, 1);
    // as = adj @ s16                   [N,64]
    spmm_csr64_f16<<<N_NODES / 4, 256, 0, stream>>>(row_ptr, cols_s, vals_s,
                                                    s16, as_);
    // out = h16 @ Wlo + bias_total + 0.5*as   [N,64]
    gemm_f16<64, 3, 0><<<MB, 256, 0, stream>>>(
        h16, WloT, bias_total, as_, out, nullptr, N_NODES, NCLASS, H2, 1);

    // ---- global min-max normalize ----
    const int n_out = N_NODES * NCLASS;
    minmax_partial<<<256, 256, 0, stream>>>(out, n_out, part);
    minmax_final<<<1, 256, 0, stream>>>(part, mm);
    normalize_kernel<<<(n_out / 4 + 255) / 256, 256, 0, stream>>>(
        (float4*)out, n_out / 4, mm);
}